// Round 3
// baseline (276.243 us; speedup 1.0000x reference)
//
#include <hip/hip_runtime.h>
#include <hip/hip_bf16.h>
#include <hip/hip_fp16.h>
#include <math.h>

// ---------------------------------------------------------------------------
// SLADGNN round 15: layer fusion. gemm_{l+1} row r depends only on agg row r,
// so agg->gemm boundaries are per-node local, not global. Fuse:
//   K3 = agg128 + gemm2 (agg out -> LDS bf16, MFMA reads LDS)
//   K4 = agg64  + gemm3
//   K5 = agg64  + head  (agg out -> Hl floats, bf16-rounded: numerics kept)
// 8 -> 5 dispatches; kills ~51MB bufH round-trip traffic + 3 launch tails.
// Keeps r14 micro-opts (perm decode, full/tail split, hoisted dinv cvt).
// ---------------------------------------------------------------------------

typedef __attribute__((ext_vector_type(8))) short short8;
typedef __attribute__((ext_vector_type(4))) float f32x4;

#define BKT_SHIFT 5
#define BKT_NODES 32
#define EPB 2048        // edges per sort_local block (391 blocks)
#define LCAP 1024       // per-bucket CSR slot capacity (mean 512, +22 sigma)
#define PREPN 28672     // prep_w elements
#define PREPB 112       // prep_w blocks

__device__ __forceinline__ short f2bs(float x) {
    __hip_bfloat16 b = __float2bfloat16(x);
    return *reinterpret_cast<short*>(&b);
}
__device__ __forceinline__ float bfround(float x) {
    return __bfloat162float(__float2bfloat16(x));
}
__device__ __forceinline__ unsigned packbf(float a, float b) {
    unsigned la = (unsigned)(unsigned short)f2bs(a);
    unsigned hb = (unsigned)(unsigned short)f2bs(b);
    return la | (hb << 16);
}

// ---- e5m2 helpers: e5m2 byte == high byte of f16 --------------------------
__device__ __forceinline__ unsigned short enc2_e5m2(float a, float b) {
    unsigned ua = __half_as_ushort(__float2half(a));
    unsigned ub = __half_as_ushort(__float2half(b));
    ua = (ua + 0x80u) >> 8;          // round-half-up on dropped byte
    ub = (ub + 0x80u) >> 8;
    return (unsigned short)((ua & 0xffu) | ((ub & 0xffu) << 8));
}
// bytes 0,1 of u -> half2
__device__ __forceinline__ __half2 dec2lo(unsigned u) {
    unsigned h = __builtin_amdgcn_perm(u, u, 0x010C000Cu);
    return *reinterpret_cast<__half2*>(&h);
}
// bytes 2,3 of u -> half2
__device__ __forceinline__ __half2 dec2hi(unsigned u) {
    unsigned h = __builtin_amdgcn_perm(u, u, 0x030C020Cu);
    return *reinterpret_cast<__half2*>(&h);
}
__device__ __forceinline__ __half2 h2shfl_xor(__half2 h, int m) {
    int i = *reinterpret_cast<int*>(&h);
    i = __shfl_xor(i, m, 64);
    return *reinterpret_cast<__half2*>(&i);
}
__device__ __forceinline__ __half2 h2shfl(__half2 h, int src) {
    int i = *reinterpret_cast<int*>(&h);
    i = __shfl(i, src, 64);
    return *reinterpret_cast<__half2*>(&i);
}

// Block-wide exclusive scan of arr[0..n) in LDS. 2 barriers per 256-chunk.
__device__ __forceinline__ void block_excl_scan(int* __restrict__ arr, int n, int t) {
    __shared__ int wsums[4];
    int lane = t & 63, wv = t >> 6;
    int carry = 0;
    for (int c0 = 0; c0 < n; c0 += 256) {
        int i = c0 + t;
        int v = (i < n) ? arr[i] : 0;
        int orig = v;
#pragma unroll
        for (int off = 1; off < 64; off <<= 1) {
            int u = __shfl_up(v, off, 64);
            if (lane >= off) v += u;
        }
        if (lane == 63) wsums[wv] = v;
        __syncthreads();
        int w0 = wsums[0], w1 = wsums[1], w2 = wsums[2], w3 = wsums[3];
        int woff = (wv > 0 ? w0 : 0) + (wv > 1 ? w1 : 0) + (wv > 2 ? w2 : 0);
        int tot = w0 + w1 + w2 + w3;
        __syncthreads();
        if (i < n) arr[i] = carry + woff + (v - orig);
        carry += tot;
    }
}

// --------------------- K1: sort_local || prep W1/W2/W3 ---------------------

__global__ __launch_bounds__(256) void sort_local_kernel(const int* __restrict__ ei, int E,
                                                         int NB, int B,
                                                         int* __restrict__ glens,
                                                         int* __restrict__ gstart,
                                                         int* __restrict__ edge_sorted,
                                                         const float* __restrict__ W1,
                                                         const float* __restrict__ W2,
                                                         const float* __restrict__ W3,
                                                         __hip_bfloat16* __restrict__ Wp1,
                                                         __hip_bfloat16* __restrict__ Wp2,
                                                         __hip_bfloat16* __restrict__ Wp3) {
    int t = threadIdx.x;
    if ((int)blockIdx.x >= B) {
        int i = ((int)blockIdx.x - B) * 256 + t;
        if (i < 16384) {                      // W1: 128x128
            int k = i >> 7, n = i & 127;
            Wp1[(((k >> 3) * 128) + n) * 8 + (k & 7)] = __float2bfloat16(W1[i]);
        } else if (i < 24576) {               // W2: 128x64
            int j = i - 16384;
            int k = j >> 6, n = j & 63;
            Wp2[(((k >> 3) * 64) + n) * 8 + (k & 7)] = __float2bfloat16(W2[j]);
        } else if (i < PREPN) {               // W3: 64x64
            int j = i - 24576;
            int k = j >> 6, n = j & 63;
            Wp3[(((k >> 3) * 64) + n) * 8 + (k & 7)] = __float2bfloat16(W3[j]);
        }
        return;
    }
    extern __shared__ int lds[];
    int* hist  = lds;                 // NB
    int* lbase = lds + NB;            // NB
    int* sortd = lds + 2 * NB;        // EPB
    int blk = blockIdx.x;
    int e0 = blk * EPB;
    int cnt = E - e0;
    if (cnt > EPB) cnt = EPB;

    for (int i = t; i < NB; i += 256) hist[i] = 0;
    __syncthreads();
    for (int i = t; i < cnt; i += 256) {
        int dst = ei[E + e0 + i];
        atomicAdd(&hist[dst >> BKT_SHIFT], 1);
    }
    __syncthreads();
    for (int i = t; i < NB; i += 256) lbase[i] = hist[i];
    __syncthreads();
    block_excl_scan(lbase, NB, t);
    __syncthreads();
    for (int i = t; i < NB; i += 256) {
        glens[(size_t)blk * NB + i] = hist[i];
        gstart[(size_t)blk * NB + i] = lbase[i];
    }
    __syncthreads();
    for (int i = t; i < cnt; i += 256) {
        int src = ei[e0 + i];
        int dst = ei[E + e0 + i];
        int pos = atomicAdd(&lbase[dst >> BKT_SHIFT], 1);
        sortd[pos] = (src << BKT_SHIFT) | (dst & (BKT_NODES - 1));
    }
    __syncthreads();
    for (int i = t; i < cnt; i += 256) edge_sorted[e0 + i] = sortd[i];
}

// --------------------- K2: csr_build || gemm1 (disjoint block ranges) ------
// gemm1 stores T1 as e5m2 bytes (unscaled).

__global__ __launch_bounds__(256) void csr_gemm1_kernel(const int* __restrict__ edge_sorted,
                                                        const int* __restrict__ glens,
                                                        const int* __restrict__ gstart,
                                                        int NB, int B, int N,
                                                        int* __restrict__ row_beg,
                                                        int* __restrict__ row_end,
                                                        float* __restrict__ dinv,
                                                        int* __restrict__ csr,
                                                        const float* __restrict__ X,
                                                        const __hip_bfloat16* __restrict__ Wp1,
                                                        unsigned char* __restrict__ T1) {
    int t = threadIdx.x;
    if ((int)blockIdx.x >= NB) {
        int bid = (int)blockIdx.x - NB;
        int lane = t & 63;
        int wave = t >> 6;
        int q = lane >> 4, l16 = lane & 15;
        int rbase = bid * 64 + wave * 16;
        int row = rbase + l16;
        int rowc = row < N ? row : N - 1;
        f32x4 acc[8];
#pragma unroll
        for (int i = 0; i < 8; ++i) acc[i] = (f32x4){0.f, 0.f, 0.f, 0.f};
#pragma unroll
        for (int kt = 0; kt < 4; ++kt) {
            int k0 = kt * 32 + q * 8;
            const float* ap = X + (size_t)rowc * 128 + k0;
            float4 lo = *(const float4*)ap;
            float4 hi = *(const float4*)(ap + 4);
            short8 afrag;
            afrag[0] = f2bs(lo.x); afrag[1] = f2bs(lo.y);
            afrag[2] = f2bs(lo.z); afrag[3] = f2bs(lo.w);
            afrag[4] = f2bs(hi.x); afrag[5] = f2bs(hi.y);
            afrag[6] = f2bs(hi.z); afrag[7] = f2bs(hi.w);
            const short8* wrow = (const short8*)(Wp1 + (size_t)(kt * 4 + q) * 128 * 8);
#pragma unroll
            for (int tt = 0; tt < 8; ++tt) {
                short8 bfrag = wrow[tt * 16 + l16];
                acc[tt] = __builtin_amdgcn_mfma_f32_16x16x32_bf16(afrag, bfrag, acc[tt], 0, 0, 0);
            }
        }
        // epilogue: pair adjacent cols (l16, l16^1) via shfl, even lanes store u16
#pragma unroll
        for (int r = 0; r < 4; ++r) {
            int gr = rbase + q * 4 + r;
#pragma unroll
            for (int tt = 0; tt < 8; ++tt) {
                float v = acc[tt][r];
                float p = __shfl_xor(v, 1, 64);
                if (((l16 & 1) == 0) && gr < N)
                    *(unsigned short*)(T1 + (size_t)gr * 128 + tt * 16 + l16) = enc2_e5m2(v, p);
            }
        }
        return;
    }
    // ---- csr_build ----
    __shared__ int lruns[512];
    __shared__ int loffs[512];
    __shared__ int sdeg[BKT_NODES];
    __shared__ int scur[BKT_NODES];
    __shared__ int raw[LCAP];
    __shared__ int srt[LCAP];
    int b = blockIdx.x;

    for (int i = t; i < 512; i += 256) {
        int v = (i < B) ? glens[(size_t)i * NB + b] : 0;
        lruns[i] = v;
        loffs[i] = v;
    }
    if (t < BKT_NODES) sdeg[t] = 0;
    __syncthreads();
    block_excl_scan(loffs, B, t);
    __syncthreads();
    int cnt = loffs[B - 1] + lruns[B - 1];
    if (cnt > LCAP) cnt = LCAP;

    for (int r = t; r < B; r += 256) {
        int len = lruns[r];
        if (len) {
            int off = loffs[r];
            int st = r * EPB + gstart[(size_t)r * NB + b];
            for (int k = 0; k < len; ++k) {
                int p = off + k;
                if (p < LCAP) raw[p] = edge_sorted[st + k];
            }
        }
    }
    __syncthreads();
    for (int i = t; i < cnt; i += 256) atomicAdd(&sdeg[raw[i] & (BKT_NODES - 1)], 1);
    __syncthreads();
    int base = b * LCAP;
    if (t < BKT_NODES) {
        int ssum = 0;
        for (int i = 0; i < t; ++i) ssum += sdeg[i];
        scur[t] = ssum;
        int node = b * BKT_NODES + t;
        if (node < N) {
            row_beg[node] = base + ssum;
            row_end[node] = base + ssum + sdeg[t];
            dinv[node] = rsqrtf((float)(sdeg[t] + 1));   // +1 self loop
        }
    }
    __syncthreads();
    for (int i = t; i < cnt; i += 256) {
        int p = raw[i];
        int pos = atomicAdd(&scur[p & (BKT_NODES - 1)], 1);
        srt[pos] = p >> BKT_SHIFT;
    }
    __syncthreads();
    for (int i = t; i < cnt; i += 256) csr[base + i] = srt[i];
}

// --------------- K3: fused agg128 (unscaled T1, dinv gather) + gemm2 -------
// Block = 64 nodes. Agg: wave w handles nodes w*16..w*16+15 sequentially,
// quarter-wave/edge, result relu(dvi*f+b1) packed bf16 -> LDS (row 136 shorts,
// 272B: 16B-aligned, 2-way banks). GEMM: 64-row MFMA <128,64>, A from LDS,
// writes prescaled e5m2 T2.
__global__ __launch_bounds__(256) void agg128_gemm2_kernel(const uint2* __restrict__ tmp,
                                                           const float* __restrict__ bias,
                                                           const float* __restrict__ dinv,
                                                           const int* __restrict__ row_beg,
                                                           const int* __restrict__ row_end,
                                                           const int* __restrict__ csr_src,
                                                           const __hip_bfloat16* __restrict__ Wp,
                                                           unsigned char* __restrict__ C, int N) {
    __shared__ unsigned short Hs[64 * 136];
    int t = threadIdx.x;
    int wave = t >> 6, lane = t & 63;
    int q = lane >> 4, sub = lane & 15;
    int nbase = (int)blockIdx.x * 64;
    __half2 zero2 = __float2half2_rn(0.f);

    for (int i = 0; i < 16; ++i) {
        int node = nbase + wave * 16 + i;
        if (node >= N) break;
        float dvi = dinv[node];
        __half2 c01 = zero2, c23 = zero2, c45 = zero2, c67 = zero2;
        if (q == 0) {
            uint2 sv = tmp[(size_t)node * 16 + sub];
            __half2 dv2 = __float2half2_rn(dvi);
            c01 = __hmul2(dec2lo(sv.x), dv2);
            c23 = __hmul2(dec2hi(sv.x), dv2);
            c45 = __hmul2(dec2lo(sv.y), dv2);
            c67 = __hmul2(dec2hi(sv.y), dv2);
        }
        int beg = row_beg[node], end = row_end[node];
        for (int j = beg; j < end; j += 64) {
            int m = end - j;
            if (m > 64) m = 64;
            int s = 0;
            float dv = 0.0f;
            if (lane < m) { s = csr_src[j + lane]; dv = dinv[s]; }
            __half2 dvh = __float2half2_rn(dv);
            int full = m >> 2;
            for (int k = 0; k < full; ++k) {
                int sk = __shfl(s, 4 * k + q, 64);
                __half2 dk2 = h2shfl(dvh, 4 * k + q);
                uint2 v = tmp[(size_t)sk * 16 + sub];
                c01 = __hfma2(dec2lo(v.x), dk2, c01);
                c23 = __hfma2(dec2hi(v.x), dk2, c23);
                c45 = __hfma2(dec2lo(v.y), dk2, c45);
                c67 = __hfma2(dec2hi(v.y), dk2, c67);
            }
            if (m & 3) {
                int e = 4 * full + q;
                int ec = (e < m) ? e : 0;
                int sk = __shfl(s, ec, 64);
                __half2 dk2 = h2shfl(dvh, ec);
                if (e >= m) dk2 = zero2;
                uint2 v = tmp[(size_t)sk * 16 + sub];
                c01 = __hfma2(dec2lo(v.x), dk2, c01);
                c23 = __hfma2(dec2hi(v.x), dk2, c23);
                c45 = __hfma2(dec2lo(v.y), dk2, c45);
                c67 = __hfma2(dec2hi(v.y), dk2, c67);
            }
        }
#pragma unroll
        for (int off = 16; off <= 32; off <<= 1) {
            c01 = __hadd2(c01, h2shfl_xor(c01, off));
            c23 = __hadd2(c23, h2shfl_xor(c23, off));
            c45 = __hadd2(c45, h2shfl_xor(c45, off));
            c67 = __hadd2(c67, h2shfl_xor(c67, off));
        }
        if (q == 0) {
            float2 f01 = __half22float2(c01);
            float2 f23 = __half22float2(c23);
            float2 f45 = __half22float2(c45);
            float2 f67 = __half22float2(c67);
            float4 b0 = *(const float4*)&bias[sub * 8];
            float4 b1 = *(const float4*)&bias[sub * 8 + 4];
            uint4 o;
            o.x = packbf(fmaxf(dvi * f01.x + b0.x, 0.f), fmaxf(dvi * f01.y + b0.y, 0.f));
            o.y = packbf(fmaxf(dvi * f23.x + b0.z, 0.f), fmaxf(dvi * f23.y + b0.w, 0.f));
            o.z = packbf(fmaxf(dvi * f45.x + b1.x, 0.f), fmaxf(dvi * f45.y + b1.y, 0.f));
            o.w = packbf(fmaxf(dvi * f67.x + b1.z, 0.f), fmaxf(dvi * f67.y + b1.w, 0.f));
            *(uint4*)&Hs[(wave * 16 + i) * 136 + sub * 8] = o;
        }
    }
    __syncthreads();

    // ---- gemm2: DI=128 DO=64, A from LDS ----
    int l16 = lane & 15;
    int rbase = nbase + wave * 16;
    f32x4 acc[4];
#pragma unroll
    for (int i = 0; i < 4; ++i) acc[i] = (f32x4){0.f, 0.f, 0.f, 0.f};
#pragma unroll
    for (int kt = 0; kt < 4; ++kt) {
        short8 afrag = *(const short8*)&Hs[(wave * 16 + l16) * 136 + kt * 32 + q * 8];
        const short8* wrow = (const short8*)(Wp + (size_t)(kt * 4 + q) * 64 * 8);
#pragma unroll
        for (int tt = 0; tt < 4; ++tt) {
            short8 bfrag = wrow[tt * 16 + l16];
            acc[tt] = __builtin_amdgcn_mfma_f32_16x16x32_bf16(afrag, bfrag, acc[tt], 0, 0, 0);
        }
    }
#pragma unroll
    for (int r = 0; r < 4; ++r) {
        int gr = rbase + q * 4 + r;
        float dv = dinv[gr < N ? gr : 0];
#pragma unroll
        for (int tt = 0; tt < 4; ++tt) {
            float v = acc[tt][r] * dv;
            float p = __shfl_xor(v, 1, 64);
            if (((l16 & 1) == 0) && gr < N)
                *(unsigned short*)(C + (size_t)gr * 64 + tt * 16 + l16) = enc2_e5m2(v, p);
        }
    }
}

// --------------- K4: fused agg64 (prescaled T2) + gemm3 --------------------
// Block = 64 nodes. Agg: eighth-wave/edge; LDS row 72 shorts (144B, aligned).
__global__ __launch_bounds__(256) void agg64_gemm3_kernel(const uint2* __restrict__ tmp,
                                                          const float* __restrict__ bias,
                                                          const float* __restrict__ dinv,
                                                          const int* __restrict__ row_beg,
                                                          const int* __restrict__ row_end,
                                                          const int* __restrict__ csr_src,
                                                          const __hip_bfloat16* __restrict__ Wp,
                                                          unsigned char* __restrict__ C, int N) {
    __shared__ unsigned short Hs[64 * 72];
    int t = threadIdx.x;
    int wave = t >> 6, lane = t & 63;
    int o8 = lane >> 3, sub8 = lane & 7;
    int nbase = (int)blockIdx.x * 64;
    __half2 one2 = __float2half2_rn(1.f);
    __half2 zero2 = __float2half2_rn(0.f);

    for (int i = 0; i < 16; ++i) {
        int node = nbase + wave * 16 + i;
        if (node >= N) break;
        float dvi = dinv[node];
        __half2 c01 = zero2, c23 = zero2, c45 = zero2, c67 = zero2;
        if (o8 == 0) {
            uint2 sv = tmp[(size_t)node * 8 + sub8];
            c01 = dec2lo(sv.x);
            c23 = dec2hi(sv.x);
            c45 = dec2lo(sv.y);
            c67 = dec2hi(sv.y);
        }
        int beg = row_beg[node], end = row_end[node];
        for (int j = beg; j < end; j += 64) {
            int m = end - j;
            if (m > 64) m = 64;
            int s = (lane < m) ? csr_src[j + lane] : 0;
            int full = m >> 3;
            for (int k = 0; k < full; ++k) {
                int sk = __shfl(s, 8 * k + o8, 64);
                uint2 v = tmp[(size_t)sk * 8 + sub8];
                c01 = __hadd2(c01, dec2lo(v.x));
                c23 = __hadd2(c23, dec2hi(v.x));
                c45 = __hadd2(c45, dec2lo(v.y));
                c67 = __hadd2(c67, dec2hi(v.y));
            }
            if (m & 7) {
                int e = 8 * full + o8;
                int ec = (e < m) ? e : 0;
                int sk = __shfl(s, ec, 64);
                uint2 v = tmp[(size_t)sk * 8 + sub8];
                __half2 msk = (e < m) ? one2 : zero2;
                c01 = __hfma2(dec2lo(v.x), msk, c01);
                c23 = __hfma2(dec2hi(v.x), msk, c23);
                c45 = __hfma2(dec2lo(v.y), msk, c45);
                c67 = __hfma2(dec2hi(v.y), msk, c67);
            }
        }
#pragma unroll
        for (int off = 8; off <= 32; off <<= 1) {
            c01 = __hadd2(c01, h2shfl_xor(c01, off));
            c23 = __hadd2(c23, h2shfl_xor(c23, off));
            c45 = __hadd2(c45, h2shfl_xor(c45, off));
            c67 = __hadd2(c67, h2shfl_xor(c67, off));
        }
        if (o8 == 0) {
            float2 f01 = __half22float2(c01);
            float2 f23 = __half22float2(c23);
            float2 f45 = __half22float2(c45);
            float2 f67 = __half22float2(c67);
            float4 b0 = *(const float4*)&bias[sub8 * 8];
            float4 b1 = *(const float4*)&bias[sub8 * 8 + 4];
            uint4 o;
            o.x = packbf(fmaxf(dvi * f01.x + b0.x, 0.f), fmaxf(dvi * f01.y + b0.y, 0.f));
            o.y = packbf(fmaxf(dvi * f23.x + b0.z, 0.f), fmaxf(dvi * f23.y + b0.w, 0.f));
            o.z = packbf(fmaxf(dvi * f45.x + b1.x, 0.f), fmaxf(dvi * f45.y + b1.y, 0.f));
            o.w = packbf(fmaxf(dvi * f67.x + b1.z, 0.f), fmaxf(dvi * f67.y + b1.w, 0.f));
            *(uint4*)&Hs[(wave * 16 + i) * 72 + sub8 * 8] = o;
        }
    }
    __syncthreads();

    // ---- gemm3: DI=64 DO=64, A from LDS ----
    int q = lane >> 4, l16 = lane & 15;
    int rbase = nbase + wave * 16;
    f32x4 acc[4];
#pragma unroll
    for (int i = 0; i < 4; ++i) acc[i] = (f32x4){0.f, 0.f, 0.f, 0.f};
#pragma unroll
    for (int kt = 0; kt < 2; ++kt) {
        short8 afrag = *(const short8*)&Hs[(wave * 16 + l16) * 72 + kt * 32 + q * 8];
        const short8* wrow = (const short8*)(Wp + (size_t)(kt * 4 + q) * 64 * 8);
#pragma unroll
        for (int tt = 0; tt < 4; ++tt) {
            short8 bfrag = wrow[tt * 16 + l16];
            acc[tt] = __builtin_amdgcn_mfma_f32_16x16x32_bf16(afrag, bfrag, acc[tt], 0, 0, 0);
        }
    }
#pragma unroll
    for (int r = 0; r < 4; ++r) {
        int gr = rbase + q * 4 + r;
        float dv = dinv[gr < N ? gr : 0];
#pragma unroll
        for (int tt = 0; tt < 4; ++tt) {
            float v = acc[tt][r] * dv;
            float p = __shfl_xor(v, 1, 64);
            if (((l16 & 1) == 0) && gr < N)
                *(unsigned short*)(C + (size_t)gr * 64 + tt * 16 + l16) = enc2_e5m2(v, p);
        }
    }
}

// --------------- K5: fused agg64 (prescaled T3) + head ---------------------
// Agg writes bf16-rounded floats straight into Hl (numerics = old pipeline).
__global__ __launch_bounds__(256) void agg64_head_kernel(const uint2* __restrict__ tmp,
                                                         const float* __restrict__ bias,
                                                         const float* __restrict__ dinv,
                                                         const int* __restrict__ row_beg,
                                                         const int* __restrict__ row_end,
                                                         const int* __restrict__ csr_src,
                                                         const float* __restrict__ protos,
                                                         const float* __restrict__ Wf0,
                                                         const float* __restrict__ bf0,
                                                         const float* __restrict__ Wf1,
                                                         const float* __restrict__ bf1,
                                                         const int* __restrict__ y,
                                                         float* __restrict__ out, int N) {
    __shared__ float Hl[64 * 65];
    __shared__ float Pl[16 * 65];
    __shared__ float hh[64];
    __shared__ float pp[16];
    __shared__ float sim[64 * 17];
    __shared__ float Wf0l[128];
    __shared__ float bf0l[8];
    __shared__ float Wf1l[8];
    __shared__ float bf1l;
    int t = threadIdx.x;
    int wave = t >> 6, lane = t & 63;
    int o8 = lane >> 3, sub8 = lane & 7;
    int n0 = (int)blockIdx.x * 64;

    // prefetch head constants (no sync needed until after agg barrier)
    for (int idx = t; idx < 16 * 64; idx += 256) {
        int r = idx >> 6, c = idx & 63;
        Pl[r * 65 + c] = protos[idx];
    }
    if (t < 128) Wf0l[t] = Wf0[t];
    if (t < 8) { bf0l[t] = bf0[t]; Wf1l[t] = Wf1[t]; }
    if (t == 0) bf1l = bf1[0];

    __half2 one2 = __float2half2_rn(1.f);
    __half2 zero2 = __float2half2_rn(0.f);
    for (int i = 0; i < 16; ++i) {
        int node = n0 + wave * 16 + i;
        if (node >= N) break;
        float dvi = dinv[node];
        __half2 c01 = zero2, c23 = zero2, c45 = zero2, c67 = zero2;
        if (o8 == 0) {
            uint2 sv = tmp[(size_t)node * 8 + sub8];
            c01 = dec2lo(sv.x);
            c23 = dec2hi(sv.x);
            c45 = dec2lo(sv.y);
            c67 = dec2hi(sv.y);
        }
        int beg = row_beg[node], end = row_end[node];
        for (int j = beg; j < end; j += 64) {
            int m = end - j;
            if (m > 64) m = 64;
            int s = (lane < m) ? csr_src[j + lane] : 0;
            int full = m >> 3;
            for (int k = 0; k < full; ++k) {
                int sk = __shfl(s, 8 * k + o8, 64);
                uint2 v = tmp[(size_t)sk * 8 + sub8];
                c01 = __hadd2(c01, dec2lo(v.x));
                c23 = __hadd2(c23, dec2hi(v.x));
                c45 = __hadd2(c45, dec2lo(v.y));
                c67 = __hadd2(c67, dec2hi(v.y));
            }
            if (m & 7) {
                int e = 8 * full + o8;
                int ec = (e < m) ? e : 0;
                int sk = __shfl(s, ec, 64);
                uint2 v = tmp[(size_t)sk * 8 + sub8];
                __half2 msk = (e < m) ? one2 : zero2;
                c01 = __hfma2(dec2lo(v.x), msk, c01);
                c23 = __hfma2(dec2hi(v.x), msk, c23);
                c45 = __hfma2(dec2lo(v.y), msk, c45);
                c67 = __hfma2(dec2hi(v.y), msk, c67);
            }
        }
#pragma unroll
        for (int off = 8; off <= 32; off <<= 1) {
            c01 = __hadd2(c01, h2shfl_xor(c01, off));
            c23 = __hadd2(c23, h2shfl_xor(c23, off));
            c45 = __hadd2(c45, h2shfl_xor(c45, off));
            c67 = __hadd2(c67, h2shfl_xor(c67, off));
        }
        if (o8 == 0) {
            float2 f01 = __half22float2(c01);
            float2 f23 = __half22float2(c23);
            float2 f45 = __half22float2(c45);
            float2 f67 = __half22float2(c67);
            float4 b0 = *(const float4*)&bias[sub8 * 8];
            float4 b1 = *(const float4*)&bias[sub8 * 8 + 4];
            float* hrow = &Hl[(wave * 16 + i) * 65 + sub8 * 8];
            hrow[0] = bfround(fmaxf(dvi * f01.x + b0.x, 0.f));
            hrow[1] = bfround(fmaxf(dvi * f01.y + b0.y, 0.f));
            hrow[2] = bfround(fmaxf(dvi * f23.x + b0.z, 0.f));
            hrow[3] = bfround(fmaxf(dvi * f23.y + b0.w, 0.f));
            hrow[4] = bfround(fmaxf(dvi * f45.x + b1.x, 0.f));
            hrow[5] = bfround(fmaxf(dvi * f45.y + b1.y, 0.f));
            hrow[6] = bfround(fmaxf(dvi * f67.x + b1.z, 0.f));
            hrow[7] = bfround(fmaxf(dvi * f67.y + b1.w, 0.f));
        }
    }
    __syncthreads();

    if (t < 64) {
        float s = 0.0f;
        for (int k = 0; k < 64; ++k) { float v = Hl[t * 65 + k]; s += v * v; }
        hh[t] = s;
    } else if (t < 80) {
        int p = t - 64;
        float s = 0.0f;
        for (int k = 0; k < 64; ++k) { float v = Pl[p * 65 + k]; s += v * v; }
        pp[p] = s;
    }
    __syncthreads();

    {
        int node = t & 63;
        int p4 = (t >> 6) * 4;
        float d0 = 0, d1 = 0, d2 = 0, d3 = 0;
        for (int k = 0; k < 64; ++k) {
            float hv = Hl[node * 65 + k];
            d0 += hv * Pl[(p4 + 0) * 65 + k];
            d1 += hv * Pl[(p4 + 1) * 65 + k];
            d2 += hv * Pl[(p4 + 2) * 65 + k];
            d3 += hv * Pl[(p4 + 3) * 65 + k];
        }
        float hhv = hh[node];
        float dd[4] = {d0, d1, d2, d3};
#pragma unroll
        for (int j = 0; j < 4; ++j) {
            float qd = hhv + pp[p4 + j] - 2.0f * dd[j];
            qd = qd > 0.0f ? qd : 0.0f;
            sim[node * 17 + p4 + j] = logf((qd + 1.0f) / (qd + 1e-4f));
        }
    }
    __syncthreads();

    if (t < 64) {
        int g = n0 + t;
        if (g < N) {
            float zacc = bf1l;
#pragma unroll
            for (int o = 0; o < 8; ++o) {
                float s = bf0l[o];
#pragma unroll
                for (int i2 = 0; i2 < 16; ++i2) s += sim[t * 17 + i2] * Wf0l[i2 * 8 + o];
                float gz = 0.5f * s * (1.0f + erff(s * 0.70710678118654752f));
                zacc += gz * Wf1l[o];
            }
            out[g] = 1.0f / (1.0f + expf(-zacc));
        }
    } else if (t < 128) {
        int g = n0 + (t - 64);
        if (g < N) out[N + g] = (float)y[g];
    }
}

// ---------------------------------------------------------------------------

extern "C" void kernel_launch(void* const* d_in, const int* in_sizes, int n_in,
                              void* d_out, int out_size, void* d_ws, size_t ws_size,
                              hipStream_t stream) {
    const float* x   = (const float*)d_in[0];
    const int*   ei  = (const int*)d_in[1];
    const int*   y   = (const int*)d_in[2];
    const float* W1  = (const float*)d_in[3];
    const float* b1  = (const float*)d_in[4];
    const float* W2  = (const float*)d_in[5];
    const float* b2  = (const float*)d_in[6];
    const float* W3  = (const float*)d_in[7];
    const float* b3  = (const float*)d_in[8];
    const float* pr  = (const float*)d_in[9];
    const float* Wf0 = (const float*)d_in[10];
    const float* bf0 = (const float*)d_in[11];
    const float* Wf1 = (const float*)d_in[12];
    const float* bf1 = (const float*)d_in[13];
    float* outp = (float*)d_out;

    const int N = in_sizes[2];       // 50000
    const int E = in_sizes[1] / 2;   // 800000
    const int NB = (N + BKT_NODES - 1) / BKT_NODES;   // 1563
    const int B = (E + EPB - 1) / EPB;                // 391 (<=512)

    char* w = (char*)d_ws;
    auto carve = [&](size_t bytes) {
        char* p = w;
        w += (bytes + 511) & ~(size_t)511;
        return p;
    };
    int*   glens   = (int*)carve((size_t)B * NB * 4);
    int*   gstart  = (int*)carve((size_t)B * NB * 4);
    int*   esort   = (int*)carve((size_t)B * EPB * 4);
    int*   row_beg = (int*)carve((size_t)N * 4);
    int*   row_end = (int*)carve((size_t)N * 4);
    float* dinv    = (float*)carve((size_t)N * 4);
    int*   csr     = (int*)carve((size_t)NB * LCAP * 4);
    __hip_bfloat16* Wp1 = (__hip_bfloat16*)carve(16384 * 2);
    __hip_bfloat16* Wp2 = (__hip_bfloat16*)carve(8192 * 2);
    __hip_bfloat16* Wp3 = (__hip_bfloat16*)carve(4096 * 2);
    unsigned char* T1b = (unsigned char*)carve((size_t)N * 128);   // e5m2
    unsigned char* T2b = (unsigned char*)carve((size_t)N * 64);    // e5m2
    unsigned char* T3b = (unsigned char*)carve((size_t)N * 64);    // e5m2

    size_t sort_lds = (size_t)(2 * NB + EPB) * 4;   // ~20.7 KB
    const int gemm1_blocks = (N + 63) / 64;          // 782
    const int node_blocks = (N + 63) / 64;           // 782

    // K1: bin+sort edges || pack weights
    sort_local_kernel<<<B + PREPB, 256, sort_lds, stream>>>(ei, E, NB, B, glens, gstart, esort,
                                                            W1, W2, W3, Wp1, Wp2, Wp3);
    // K2: CSR build || gemm1 (unscaled T1 -> fp8)
    csr_gemm1_kernel<<<NB + gemm1_blocks, 256, 0, stream>>>(esort, glens, gstart, NB, B, N,
                                                            row_beg, row_end, dinv, csr,
                                                            x, Wp1, T1b);
    // K3: agg128 (dinv gather) + gemm2 -> prescaled T2
    agg128_gemm2_kernel<<<node_blocks, 256, 0, stream>>>((const uint2*)T1b, b1, dinv,
                                                         row_beg, row_end, csr, Wp2, T2b, N);
    // K4: agg64 + gemm3 -> prescaled T3
    agg64_gemm3_kernel<<<node_blocks, 256, 0, stream>>>((const uint2*)T2b, b2, dinv,
                                                        row_beg, row_end, csr, Wp3, T3b, N);
    // K5: agg64 + head -> out
    agg64_head_kernel<<<node_blocks, 256, 0, stream>>>((const uint2*)T3b, b3, dinv,
                                                       row_beg, row_end, csr,
                                                       pr, Wf0, bf0, Wf1, bf1, y, outp, N);
}

// Round 4
// 228.999 us; speedup vs baseline: 1.2063x; 1.2063x over previous
//
#include <hip/hip_runtime.h>
#include <hip/hip_bf16.h>
#include <hip/hip_fp16.h>
#include <math.h>

// ---------------------------------------------------------------------------
// SLADGNN round 16: fix r15's fusion occupancy collapse (29% -> latency-bound,
// 62us agg128_gemm2). Fused kernels now use 1024-thread blocks: 16 waves x
// 4 nodes each (vs 4 waves x 16 nodes). 2 blocks/CU = 32 waves/CU = the same
// full-occupancy regime as the proven separate aggs. GEMM phase: wave w ->
// (row-tile w>>2, col-tile w&3), 4/2 MFMA per wave. Head gates 256-thread
// stages with if(t<256) between block barriers.
// ---------------------------------------------------------------------------

typedef __attribute__((ext_vector_type(8))) short short8;
typedef __attribute__((ext_vector_type(4))) float f32x4;

#define BKT_SHIFT 5
#define BKT_NODES 32
#define EPB 2048        // edges per sort_local block (391 blocks)
#define LCAP 1024       // per-bucket CSR slot capacity (mean 512, +22 sigma)
#define PREPN 28672     // prep_w elements
#define PREPB 112       // prep_w blocks

__device__ __forceinline__ short f2bs(float x) {
    __hip_bfloat16 b = __float2bfloat16(x);
    return *reinterpret_cast<short*>(&b);
}
__device__ __forceinline__ float bfround(float x) {
    return __bfloat162float(__float2bfloat16(x));
}
__device__ __forceinline__ unsigned packbf(float a, float b) {
    unsigned la = (unsigned)(unsigned short)f2bs(a);
    unsigned hb = (unsigned)(unsigned short)f2bs(b);
    return la | (hb << 16);
}

// ---- e5m2 helpers: e5m2 byte == high byte of f16 --------------------------
__device__ __forceinline__ unsigned short enc2_e5m2(float a, float b) {
    unsigned ua = __half_as_ushort(__float2half(a));
    unsigned ub = __half_as_ushort(__float2half(b));
    ua = (ua + 0x80u) >> 8;          // round-half-up on dropped byte
    ub = (ub + 0x80u) >> 8;
    return (unsigned short)((ua & 0xffu) | ((ub & 0xffu) << 8));
}
// bytes 0,1 of u -> half2
__device__ __forceinline__ __half2 dec2lo(unsigned u) {
    unsigned h = __builtin_amdgcn_perm(u, u, 0x010C000Cu);
    return *reinterpret_cast<__half2*>(&h);
}
// bytes 2,3 of u -> half2
__device__ __forceinline__ __half2 dec2hi(unsigned u) {
    unsigned h = __builtin_amdgcn_perm(u, u, 0x030C020Cu);
    return *reinterpret_cast<__half2*>(&h);
}
__device__ __forceinline__ __half2 h2shfl_xor(__half2 h, int m) {
    int i = *reinterpret_cast<int*>(&h);
    i = __shfl_xor(i, m, 64);
    return *reinterpret_cast<__half2*>(&i);
}
__device__ __forceinline__ __half2 h2shfl(__half2 h, int src) {
    int i = *reinterpret_cast<int*>(&h);
    i = __shfl(i, src, 64);
    return *reinterpret_cast<__half2*>(&i);
}

// Block-wide exclusive scan of arr[0..n) in LDS (256-thread blocks only).
__device__ __forceinline__ void block_excl_scan(int* __restrict__ arr, int n, int t) {
    __shared__ int wsums[4];
    int lane = t & 63, wv = t >> 6;
    int carry = 0;
    for (int c0 = 0; c0 < n; c0 += 256) {
        int i = c0 + t;
        int v = (i < n) ? arr[i] : 0;
        int orig = v;
#pragma unroll
        for (int off = 1; off < 64; off <<= 1) {
            int u = __shfl_up(v, off, 64);
            if (lane >= off) v += u;
        }
        if (lane == 63) wsums[wv] = v;
        __syncthreads();
        int w0 = wsums[0], w1 = wsums[1], w2 = wsums[2], w3 = wsums[3];
        int woff = (wv > 0 ? w0 : 0) + (wv > 1 ? w1 : 0) + (wv > 2 ? w2 : 0);
        int tot = w0 + w1 + w2 + w3;
        __syncthreads();
        if (i < n) arr[i] = carry + woff + (v - orig);
        carry += tot;
    }
}

// --------------------- K1: sort_local || prep W1/W2/W3 ---------------------

__global__ __launch_bounds__(256) void sort_local_kernel(const int* __restrict__ ei, int E,
                                                         int NB, int B,
                                                         int* __restrict__ glens,
                                                         int* __restrict__ gstart,
                                                         int* __restrict__ edge_sorted,
                                                         const float* __restrict__ W1,
                                                         const float* __restrict__ W2,
                                                         const float* __restrict__ W3,
                                                         __hip_bfloat16* __restrict__ Wp1,
                                                         __hip_bfloat16* __restrict__ Wp2,
                                                         __hip_bfloat16* __restrict__ Wp3) {
    int t = threadIdx.x;
    if ((int)blockIdx.x >= B) {
        int i = ((int)blockIdx.x - B) * 256 + t;
        if (i < 16384) {                      // W1: 128x128
            int k = i >> 7, n = i & 127;
            Wp1[(((k >> 3) * 128) + n) * 8 + (k & 7)] = __float2bfloat16(W1[i]);
        } else if (i < 24576) {               // W2: 128x64
            int j = i - 16384;
            int k = j >> 6, n = j & 63;
            Wp2[(((k >> 3) * 64) + n) * 8 + (k & 7)] = __float2bfloat16(W2[j]);
        } else if (i < PREPN) {               // W3: 64x64
            int j = i - 24576;
            int k = j >> 6, n = j & 63;
            Wp3[(((k >> 3) * 64) + n) * 8 + (k & 7)] = __float2bfloat16(W3[j]);
        }
        return;
    }
    extern __shared__ int lds[];
    int* hist  = lds;                 // NB
    int* lbase = lds + NB;            // NB
    int* sortd = lds + 2 * NB;        // EPB
    int blk = blockIdx.x;
    int e0 = blk * EPB;
    int cnt = E - e0;
    if (cnt > EPB) cnt = EPB;

    for (int i = t; i < NB; i += 256) hist[i] = 0;
    __syncthreads();
    for (int i = t; i < cnt; i += 256) {
        int dst = ei[E + e0 + i];
        atomicAdd(&hist[dst >> BKT_SHIFT], 1);
    }
    __syncthreads();
    for (int i = t; i < NB; i += 256) lbase[i] = hist[i];
    __syncthreads();
    block_excl_scan(lbase, NB, t);
    __syncthreads();
    for (int i = t; i < NB; i += 256) {
        glens[(size_t)blk * NB + i] = hist[i];
        gstart[(size_t)blk * NB + i] = lbase[i];
    }
    __syncthreads();
    for (int i = t; i < cnt; i += 256) {
        int src = ei[e0 + i];
        int dst = ei[E + e0 + i];
        int pos = atomicAdd(&lbase[dst >> BKT_SHIFT], 1);
        sortd[pos] = (src << BKT_SHIFT) | (dst & (BKT_NODES - 1));
    }
    __syncthreads();
    for (int i = t; i < cnt; i += 256) edge_sorted[e0 + i] = sortd[i];
}

// --------------------- K2: csr_build || gemm1 (disjoint block ranges) ------
// gemm1 stores T1 as e5m2 bytes (unscaled).

__global__ __launch_bounds__(256) void csr_gemm1_kernel(const int* __restrict__ edge_sorted,
                                                        const int* __restrict__ glens,
                                                        const int* __restrict__ gstart,
                                                        int NB, int B, int N,
                                                        int* __restrict__ row_beg,
                                                        int* __restrict__ row_end,
                                                        float* __restrict__ dinv,
                                                        int* __restrict__ csr,
                                                        const float* __restrict__ X,
                                                        const __hip_bfloat16* __restrict__ Wp1,
                                                        unsigned char* __restrict__ T1) {
    int t = threadIdx.x;
    if ((int)blockIdx.x >= NB) {
        int bid = (int)blockIdx.x - NB;
        int lane = t & 63;
        int wave = t >> 6;
        int q = lane >> 4, l16 = lane & 15;
        int rbase = bid * 64 + wave * 16;
        int row = rbase + l16;
        int rowc = row < N ? row : N - 1;
        f32x4 acc[8];
#pragma unroll
        for (int i = 0; i < 8; ++i) acc[i] = (f32x4){0.f, 0.f, 0.f, 0.f};
#pragma unroll
        for (int kt = 0; kt < 4; ++kt) {
            int k0 = kt * 32 + q * 8;
            const float* ap = X + (size_t)rowc * 128 + k0;
            float4 lo = *(const float4*)ap;
            float4 hi = *(const float4*)(ap + 4);
            short8 afrag;
            afrag[0] = f2bs(lo.x); afrag[1] = f2bs(lo.y);
            afrag[2] = f2bs(lo.z); afrag[3] = f2bs(lo.w);
            afrag[4] = f2bs(hi.x); afrag[5] = f2bs(hi.y);
            afrag[6] = f2bs(hi.z); afrag[7] = f2bs(hi.w);
            const short8* wrow = (const short8*)(Wp1 + (size_t)(kt * 4 + q) * 128 * 8);
#pragma unroll
            for (int tt = 0; tt < 8; ++tt) {
                short8 bfrag = wrow[tt * 16 + l16];
                acc[tt] = __builtin_amdgcn_mfma_f32_16x16x32_bf16(afrag, bfrag, acc[tt], 0, 0, 0);
            }
        }
        // epilogue: pair adjacent cols (l16, l16^1) via shfl, even lanes store u16
#pragma unroll
        for (int r = 0; r < 4; ++r) {
            int gr = rbase + q * 4 + r;
#pragma unroll
            for (int tt = 0; tt < 8; ++tt) {
                float v = acc[tt][r];
                float p = __shfl_xor(v, 1, 64);
                if (((l16 & 1) == 0) && gr < N)
                    *(unsigned short*)(T1 + (size_t)gr * 128 + tt * 16 + l16) = enc2_e5m2(v, p);
            }
        }
        return;
    }
    // ---- csr_build ----
    __shared__ int lruns[512];
    __shared__ int loffs[512];
    __shared__ int sdeg[BKT_NODES];
    __shared__ int scur[BKT_NODES];
    __shared__ int raw[LCAP];
    __shared__ int srt[LCAP];
    int b = blockIdx.x;

    for (int i = t; i < 512; i += 256) {
        int v = (i < B) ? glens[(size_t)i * NB + b] : 0;
        lruns[i] = v;
        loffs[i] = v;
    }
    if (t < BKT_NODES) sdeg[t] = 0;
    __syncthreads();
    block_excl_scan(loffs, B, t);
    __syncthreads();
    int cnt = loffs[B - 1] + lruns[B - 1];
    if (cnt > LCAP) cnt = LCAP;

    for (int r = t; r < B; r += 256) {
        int len = lruns[r];
        if (len) {
            int off = loffs[r];
            int st = r * EPB + gstart[(size_t)r * NB + b];
            for (int k = 0; k < len; ++k) {
                int p = off + k;
                if (p < LCAP) raw[p] = edge_sorted[st + k];
            }
        }
    }
    __syncthreads();
    for (int i = t; i < cnt; i += 256) atomicAdd(&sdeg[raw[i] & (BKT_NODES - 1)], 1);
    __syncthreads();
    int base = b * LCAP;
    if (t < BKT_NODES) {
        int ssum = 0;
        for (int i = 0; i < t; ++i) ssum += sdeg[i];
        scur[t] = ssum;
        int node = b * BKT_NODES + t;
        if (node < N) {
            row_beg[node] = base + ssum;
            row_end[node] = base + ssum + sdeg[t];
            dinv[node] = rsqrtf((float)(sdeg[t] + 1));   // +1 self loop
        }
    }
    __syncthreads();
    for (int i = t; i < cnt; i += 256) {
        int p = raw[i];
        int pos = atomicAdd(&scur[p & (BKT_NODES - 1)], 1);
        srt[pos] = p >> BKT_SHIFT;
    }
    __syncthreads();
    for (int i = t; i < cnt; i += 256) csr[base + i] = srt[i];
}

// --------------- K3: fused agg128 (unscaled T1, dinv gather) + gemm2 -------
// 1024 threads: agg = 16 waves x 4 nodes (full occupancy), quarter-wave/edge.
// Results packed bf16 -> LDS (row 136 shorts, 272B: 2-way banks = free).
// GEMM: wave w -> rows (w>>2)*16, cols (w&3)*16; 4 MFMA; prescaled e5m2 out.
__global__ __launch_bounds__(1024) void agg128_gemm2_kernel(const uint2* __restrict__ tmp,
                                                            const float* __restrict__ bias,
                                                            const float* __restrict__ dinv,
                                                            const int* __restrict__ row_beg,
                                                            const int* __restrict__ row_end,
                                                            const int* __restrict__ csr_src,
                                                            const __hip_bfloat16* __restrict__ Wp,
                                                            unsigned char* __restrict__ C, int N) {
    __shared__ unsigned short Hs[64 * 136];
    int t = threadIdx.x;
    int wave = t >> 6, lane = t & 63;
    int q = lane >> 4, sub = lane & 15;
    int nbase = (int)blockIdx.x * 64;
    __half2 zero2 = __float2half2_rn(0.f);

#pragma unroll
    for (int i = 0; i < 4; ++i) {
        int node = nbase + wave * 4 + i;
        if (node >= N) break;
        float dvi = dinv[node];
        __half2 c01 = zero2, c23 = zero2, c45 = zero2, c67 = zero2;
        if (q == 0) {
            uint2 sv = tmp[(size_t)node * 16 + sub];
            __half2 dv2 = __float2half2_rn(dvi);
            c01 = __hmul2(dec2lo(sv.x), dv2);
            c23 = __hmul2(dec2hi(sv.x), dv2);
            c45 = __hmul2(dec2lo(sv.y), dv2);
            c67 = __hmul2(dec2hi(sv.y), dv2);
        }
        int beg = row_beg[node], end = row_end[node];
        for (int j = beg; j < end; j += 64) {
            int m = end - j;
            if (m > 64) m = 64;
            int s = 0;
            float dv = 0.0f;
            if (lane < m) { s = csr_src[j + lane]; dv = dinv[s]; }
            __half2 dvh = __float2half2_rn(dv);
            int full = m >> 2;
            for (int k = 0; k < full; ++k) {
                int sk = __shfl(s, 4 * k + q, 64);
                __half2 dk2 = h2shfl(dvh, 4 * k + q);
                uint2 v = tmp[(size_t)sk * 16 + sub];
                c01 = __hfma2(dec2lo(v.x), dk2, c01);
                c23 = __hfma2(dec2hi(v.x), dk2, c23);
                c45 = __hfma2(dec2lo(v.y), dk2, c45);
                c67 = __hfma2(dec2hi(v.y), dk2, c67);
            }
            if (m & 3) {
                int e = 4 * full + q;
                int ec = (e < m) ? e : 0;
                int sk = __shfl(s, ec, 64);
                __half2 dk2 = h2shfl(dvh, ec);
                if (e >= m) dk2 = zero2;
                uint2 v = tmp[(size_t)sk * 16 + sub];
                c01 = __hfma2(dec2lo(v.x), dk2, c01);
                c23 = __hfma2(dec2hi(v.x), dk2, c23);
                c45 = __hfma2(dec2lo(v.y), dk2, c45);
                c67 = __hfma2(dec2hi(v.y), dk2, c67);
            }
        }
#pragma unroll
        for (int off = 16; off <= 32; off <<= 1) {
            c01 = __hadd2(c01, h2shfl_xor(c01, off));
            c23 = __hadd2(c23, h2shfl_xor(c23, off));
            c45 = __hadd2(c45, h2shfl_xor(c45, off));
            c67 = __hadd2(c67, h2shfl_xor(c67, off));
        }
        if (q == 0) {
            float2 f01 = __half22float2(c01);
            float2 f23 = __half22float2(c23);
            float2 f45 = __half22float2(c45);
            float2 f67 = __half22float2(c67);
            float4 b0 = *(const float4*)&bias[sub * 8];
            float4 b1 = *(const float4*)&bias[sub * 8 + 4];
            uint4 o;
            o.x = packbf(fmaxf(dvi * f01.x + b0.x, 0.f), fmaxf(dvi * f01.y + b0.y, 0.f));
            o.y = packbf(fmaxf(dvi * f23.x + b0.z, 0.f), fmaxf(dvi * f23.y + b0.w, 0.f));
            o.z = packbf(fmaxf(dvi * f45.x + b1.x, 0.f), fmaxf(dvi * f45.y + b1.y, 0.f));
            o.w = packbf(fmaxf(dvi * f67.x + b1.z, 0.f), fmaxf(dvi * f67.y + b1.w, 0.f));
            *(uint4*)&Hs[(wave * 4 + i) * 136 + sub * 8] = o;
        }
    }
    __syncthreads();

    // ---- gemm2: DI=128 DO=64. wave -> (row-tile, col-tile) ----
    int rt = wave >> 2, ct = wave & 3;
    int l16 = lane & 15;
    int rbase = nbase + rt * 16;
    f32x4 acc = (f32x4){0.f, 0.f, 0.f, 0.f};
#pragma unroll
    for (int kt = 0; kt < 4; ++kt) {
        short8 afrag = *(const short8*)&Hs[(rt * 16 + l16) * 136 + kt * 32 + q * 8];
        const short8* wrow = (const short8*)(Wp + (size_t)(kt * 4 + q) * 64 * 8);
        short8 bfrag = wrow[ct * 16 + l16];
        acc = __builtin_amdgcn_mfma_f32_16x16x32_bf16(afrag, bfrag, acc, 0, 0, 0);
    }
#pragma unroll
    for (int r = 0; r < 4; ++r) {
        int gr = rbase + q * 4 + r;
        float dv = dinv[gr < N ? gr : 0];
        float v = acc[r] * dv;
        float p = __shfl_xor(v, 1, 64);
        if (((l16 & 1) == 0) && gr < N)
            *(unsigned short*)(C + (size_t)gr * 64 + ct * 16 + l16) = enc2_e5m2(v, p);
    }
}

// --------------- K4: fused agg64 (prescaled T2) + gemm3 --------------------
// 1024 threads: agg = 16 waves x 4 nodes, eighth-wave/edge. LDS row 72 shorts.
__global__ __launch_bounds__(1024) void agg64_gemm3_kernel(const uint2* __restrict__ tmp,
                                                           const float* __restrict__ bias,
                                                           const float* __restrict__ dinv,
                                                           const int* __restrict__ row_beg,
                                                           const int* __restrict__ row_end,
                                                           const int* __restrict__ csr_src,
                                                           const __hip_bfloat16* __restrict__ Wp,
                                                           unsigned char* __restrict__ C, int N) {
    __shared__ unsigned short Hs[64 * 72];
    int t = threadIdx.x;
    int wave = t >> 6, lane = t & 63;
    int o8 = lane >> 3, sub8 = lane & 7;
    int nbase = (int)blockIdx.x * 64;
    __half2 one2 = __float2half2_rn(1.f);
    __half2 zero2 = __float2half2_rn(0.f);

#pragma unroll
    for (int i = 0; i < 4; ++i) {
        int node = nbase + wave * 4 + i;
        if (node >= N) break;
        float dvi = dinv[node];
        __half2 c01 = zero2, c23 = zero2, c45 = zero2, c67 = zero2;
        if (o8 == 0) {
            uint2 sv = tmp[(size_t)node * 8 + sub8];
            c01 = dec2lo(sv.x);
            c23 = dec2hi(sv.x);
            c45 = dec2lo(sv.y);
            c67 = dec2hi(sv.y);
        }
        int beg = row_beg[node], end = row_end[node];
        for (int j = beg; j < end; j += 64) {
            int m = end - j;
            if (m > 64) m = 64;
            int s = (lane < m) ? csr_src[j + lane] : 0;
            int full = m >> 3;
            for (int k = 0; k < full; ++k) {
                int sk = __shfl(s, 8 * k + o8, 64);
                uint2 v = tmp[(size_t)sk * 8 + sub8];
                c01 = __hadd2(c01, dec2lo(v.x));
                c23 = __hadd2(c23, dec2hi(v.x));
                c45 = __hadd2(c45, dec2lo(v.y));
                c67 = __hadd2(c67, dec2hi(v.y));
            }
            if (m & 7) {
                int e = 8 * full + o8;
                int ec = (e < m) ? e : 0;
                int sk = __shfl(s, ec, 64);
                uint2 v = tmp[(size_t)sk * 8 + sub8];
                __half2 msk = (e < m) ? one2 : zero2;
                c01 = __hfma2(dec2lo(v.x), msk, c01);
                c23 = __hfma2(dec2hi(v.x), msk, c23);
                c45 = __hfma2(dec2lo(v.y), msk, c45);
                c67 = __hfma2(dec2hi(v.y), msk, c67);
            }
        }
#pragma unroll
        for (int off = 8; off <= 32; off <<= 1) {
            c01 = __hadd2(c01, h2shfl_xor(c01, off));
            c23 = __hadd2(c23, h2shfl_xor(c23, off));
            c45 = __hadd2(c45, h2shfl_xor(c45, off));
            c67 = __hadd2(c67, h2shfl_xor(c67, off));
        }
        if (o8 == 0) {
            float2 f01 = __half22float2(c01);
            float2 f23 = __half22float2(c23);
            float2 f45 = __half22float2(c45);
            float2 f67 = __half22float2(c67);
            float4 b0 = *(const float4*)&bias[sub8 * 8];
            float4 b1 = *(const float4*)&bias[sub8 * 8 + 4];
            uint4 o;
            o.x = packbf(fmaxf(dvi * f01.x + b0.x, 0.f), fmaxf(dvi * f01.y + b0.y, 0.f));
            o.y = packbf(fmaxf(dvi * f23.x + b0.z, 0.f), fmaxf(dvi * f23.y + b0.w, 0.f));
            o.z = packbf(fmaxf(dvi * f45.x + b1.x, 0.f), fmaxf(dvi * f45.y + b1.y, 0.f));
            o.w = packbf(fmaxf(dvi * f67.x + b1.z, 0.f), fmaxf(dvi * f67.y + b1.w, 0.f));
            *(uint4*)&Hs[(wave * 4 + i) * 72 + sub8 * 8] = o;
        }
    }
    __syncthreads();

    // ---- gemm3: DI=64 DO=64. wave -> (row-tile, col-tile) ----
    int rt = wave >> 2, ct = wave & 3;
    int q = lane >> 4, l16 = lane & 15;
    int rbase = nbase + rt * 16;
    f32x4 acc = (f32x4){0.f, 0.f, 0.f, 0.f};
#pragma unroll
    for (int kt = 0; kt < 2; ++kt) {
        short8 afrag = *(const short8*)&Hs[(rt * 16 + l16) * 72 + kt * 32 + q * 8];
        const short8* wrow = (const short8*)(Wp + (size_t)(kt * 4 + q) * 64 * 8);
        short8 bfrag = wrow[ct * 16 + l16];
        acc = __builtin_amdgcn_mfma_f32_16x16x32_bf16(afrag, bfrag, acc, 0, 0, 0);
    }
#pragma unroll
    for (int r = 0; r < 4; ++r) {
        int gr = rbase + q * 4 + r;
        float dv = dinv[gr < N ? gr : 0];
        float v = acc[r] * dv;
        float p = __shfl_xor(v, 1, 64);
        if (((l16 & 1) == 0) && gr < N)
            *(unsigned short*)(C + (size_t)gr * 64 + ct * 16 + l16) = enc2_e5m2(v, p);
    }
}

// --------------- K5: fused agg64 (prescaled T3) + head ---------------------
// 1024 threads: agg = 16 waves x 4 nodes; head stages gate to t<256 between
// block-wide barriers. Agg writes bf16-rounded floats into Hl (numerics kept).
__global__ __launch_bounds__(1024) void agg64_head_kernel(const uint2* __restrict__ tmp,
                                                          const float* __restrict__ bias,
                                                          const float* __restrict__ dinv,
                                                          const int* __restrict__ row_beg,
                                                          const int* __restrict__ row_end,
                                                          const int* __restrict__ csr_src,
                                                          const float* __restrict__ protos,
                                                          const float* __restrict__ Wf0,
                                                          const float* __restrict__ bf0,
                                                          const float* __restrict__ Wf1,
                                                          const float* __restrict__ bf1,
                                                          const int* __restrict__ y,
                                                          float* __restrict__ out, int N) {
    __shared__ float Hl[64 * 65];
    __shared__ float Pl[16 * 65];
    __shared__ float hh[64];
    __shared__ float pp[16];
    __shared__ float sim[64 * 17];
    __shared__ float Wf0l[128];
    __shared__ float bf0l[8];
    __shared__ float Wf1l[8];
    __shared__ float bf1l;
    int t = threadIdx.x;
    int wave = t >> 6, lane = t & 63;
    int o8 = lane >> 3, sub8 = lane & 7;
    int n0 = (int)blockIdx.x * 64;

    // prefetch head constants (all 1024 threads; 16*64 = 1024 exactly)
    if (t < 16 * 64) {
        int r = t >> 6, c = t & 63;
        Pl[r * 65 + c] = protos[t];
    }
    if (t < 128) Wf0l[t] = Wf0[t];
    if (t < 8) { bf0l[t] = bf0[t]; Wf1l[t] = Wf1[t]; }
    if (t == 0) bf1l = bf1[0];

    __half2 one2 = __float2half2_rn(1.f);
    __half2 zero2 = __float2half2_rn(0.f);
#pragma unroll
    for (int i = 0; i < 4; ++i) {
        int node = n0 + wave * 4 + i;
        if (node >= N) break;
        float dvi = dinv[node];
        __half2 c01 = zero2, c23 = zero2, c45 = zero2, c67 = zero2;
        if (o8 == 0) {
            uint2 sv = tmp[(size_t)node * 8 + sub8];
            c01 = dec2lo(sv.x);
            c23 = dec2hi(sv.x);
            c45 = dec2lo(sv.y);
            c67 = dec2hi(sv.y);
        }
        int beg = row_beg[node], end = row_end[node];
        for (int j = beg; j < end; j += 64) {
            int m = end - j;
            if (m > 64) m = 64;
            int s = (lane < m) ? csr_src[j + lane] : 0;
            int full = m >> 3;
            for (int k = 0; k < full; ++k) {
                int sk = __shfl(s, 8 * k + o8, 64);
                uint2 v = tmp[(size_t)sk * 8 + sub8];
                c01 = __hadd2(c01, dec2lo(v.x));
                c23 = __hadd2(c23, dec2hi(v.x));
                c45 = __hadd2(c45, dec2lo(v.y));
                c67 = __hadd2(c67, dec2hi(v.y));
            }
            if (m & 7) {
                int e = 8 * full + o8;
                int ec = (e < m) ? e : 0;
                int sk = __shfl(s, ec, 64);
                uint2 v = tmp[(size_t)sk * 8 + sub8];
                __half2 msk = (e < m) ? one2 : zero2;
                c01 = __hfma2(dec2lo(v.x), msk, c01);
                c23 = __hfma2(dec2hi(v.x), msk, c23);
                c45 = __hfma2(dec2lo(v.y), msk, c45);
                c67 = __hfma2(dec2hi(v.y), msk, c67);
            }
        }
#pragma unroll
        for (int off = 8; off <= 32; off <<= 1) {
            c01 = __hadd2(c01, h2shfl_xor(c01, off));
            c23 = __hadd2(c23, h2shfl_xor(c23, off));
            c45 = __hadd2(c45, h2shfl_xor(c45, off));
            c67 = __hadd2(c67, h2shfl_xor(c67, off));
        }
        if (o8 == 0) {
            float2 f01 = __half22float2(c01);
            float2 f23 = __half22float2(c23);
            float2 f45 = __half22float2(c45);
            float2 f67 = __half22float2(c67);
            float4 b0 = *(const float4*)&bias[sub8 * 8];
            float4 b1 = *(const float4*)&bias[sub8 * 8 + 4];
            float* hrow = &Hl[(wave * 4 + i) * 65 + sub8 * 8];
            hrow[0] = bfround(fmaxf(dvi * f01.x + b0.x, 0.f));
            hrow[1] = bfround(fmaxf(dvi * f01.y + b0.y, 0.f));
            hrow[2] = bfround(fmaxf(dvi * f23.x + b0.z, 0.f));
            hrow[3] = bfround(fmaxf(dvi * f23.y + b0.w, 0.f));
            hrow[4] = bfround(fmaxf(dvi * f45.x + b1.x, 0.f));
            hrow[5] = bfround(fmaxf(dvi * f45.y + b1.y, 0.f));
            hrow[6] = bfround(fmaxf(dvi * f67.x + b1.z, 0.f));
            hrow[7] = bfround(fmaxf(dvi * f67.y + b1.w, 0.f));
        }
    }
    __syncthreads();

    if (t < 64) {
        float s = 0.0f;
        for (int k = 0; k < 64; ++k) { float v = Hl[t * 65 + k]; s += v * v; }
        hh[t] = s;
    } else if (t < 80) {
        int p = t - 64;
        float s = 0.0f;
        for (int k = 0; k < 64; ++k) { float v = Pl[p * 65 + k]; s += v * v; }
        pp[p] = s;
    }
    __syncthreads();

    if (t < 256) {
        int node = t & 63;
        int p4 = (t >> 6) * 4;
        float d0 = 0, d1 = 0, d2 = 0, d3 = 0;
        for (int k = 0; k < 64; ++k) {
            float hv = Hl[node * 65 + k];
            d0 += hv * Pl[(p4 + 0) * 65 + k];
            d1 += hv * Pl[(p4 + 1) * 65 + k];
            d2 += hv * Pl[(p4 + 2) * 65 + k];
            d3 += hv * Pl[(p4 + 3) * 65 + k];
        }
        float hhv = hh[node];
        float dd[4] = {d0, d1, d2, d3};
#pragma unroll
        for (int j = 0; j < 4; ++j) {
            float qd = hhv + pp[p4 + j] - 2.0f * dd[j];
            qd = qd > 0.0f ? qd : 0.0f;
            sim[node * 17 + p4 + j] = logf((qd + 1.0f) / (qd + 1e-4f));
        }
    }
    __syncthreads();

    if (t < 64) {
        int g = n0 + t;
        if (g < N) {
            float zacc = bf1l;
#pragma unroll
            for (int o = 0; o < 8; ++o) {
                float s = bf0l[o];
#pragma unroll
                for (int i2 = 0; i2 < 16; ++i2) s += sim[t * 17 + i2] * Wf0l[i2 * 8 + o];
                float gz = 0.5f * s * (1.0f + erff(s * 0.70710678118654752f));
                zacc += gz * Wf1l[o];
            }
            out[g] = 1.0f / (1.0f + expf(-zacc));
        }
    } else if (t < 128) {
        int g = n0 + (t - 64);
        if (g < N) out[N + g] = (float)y[g];
    }
}

// ---------------------------------------------------------------------------

extern "C" void kernel_launch(void* const* d_in, const int* in_sizes, int n_in,
                              void* d_out, int out_size, void* d_ws, size_t ws_size,
                              hipStream_t stream) {
    const float* x   = (const float*)d_in[0];
    const int*   ei  = (const int*)d_in[1];
    const int*   y   = (const int*)d_in[2];
    const float* W1  = (const float*)d_in[3];
    const float* b1  = (const float*)d_in[4];
    const float* W2  = (const float*)d_in[5];
    const float* b2  = (const float*)d_in[6];
    const float* W3  = (const float*)d_in[7];
    const float* b3  = (const float*)d_in[8];
    const float* pr  = (const float*)d_in[9];
    const float* Wf0 = (const float*)d_in[10];
    const float* bf0 = (const float*)d_in[11];
    const float* Wf1 = (const float*)d_in[12];
    const float* bf1 = (const float*)d_in[13];
    float* outp = (float*)d_out;

    const int N = in_sizes[2];       // 50000
    const int E = in_sizes[1] / 2;   // 800000
    const int NB = (N + BKT_NODES - 1) / BKT_NODES;   // 1563
    const int B = (E + EPB - 1) / EPB;                // 391 (<=512)

    char* w = (char*)d_ws;
    auto carve = [&](size_t bytes) {
        char* p = w;
        w += (bytes + 511) & ~(size_t)511;
        return p;
    };
    int*   glens   = (int*)carve((size_t)B * NB * 4);
    int*   gstart  = (int*)carve((size_t)B * NB * 4);
    int*   esort   = (int*)carve((size_t)B * EPB * 4);
    int*   row_beg = (int*)carve((size_t)N * 4);
    int*   row_end = (int*)carve((size_t)N * 4);
    float* dinv    = (float*)carve((size_t)N * 4);
    int*   csr     = (int*)carve((size_t)NB * LCAP * 4);
    __hip_bfloat16* Wp1 = (__hip_bfloat16*)carve(16384 * 2);
    __hip_bfloat16* Wp2 = (__hip_bfloat16*)carve(8192 * 2);
    __hip_bfloat16* Wp3 = (__hip_bfloat16*)carve(4096 * 2);
    unsigned char* T1b = (unsigned char*)carve((size_t)N * 128);   // e5m2
    unsigned char* T2b = (unsigned char*)carve((size_t)N * 64);    // e5m2
    unsigned char* T3b = (unsigned char*)carve((size_t)N * 64);    // e5m2

    size_t sort_lds = (size_t)(2 * NB + EPB) * 4;   // ~20.7 KB
    const int gemm1_blocks = (N + 63) / 64;          // 782
    const int node_blocks = (N + 63) / 64;           // 782

    // K1: bin+sort edges || pack weights
    sort_local_kernel<<<B + PREPB, 256, sort_lds, stream>>>(ei, E, NB, B, glens, gstart, esort,
                                                            W1, W2, W3, Wp1, Wp2, Wp3);
    // K2: CSR build || gemm1 (unscaled T1 -> fp8)
    csr_gemm1_kernel<<<NB + gemm1_blocks, 256, 0, stream>>>(esort, glens, gstart, NB, B, N,
                                                            row_beg, row_end, dinv, csr,
                                                            x, Wp1, T1b);
    // K3: agg128 (dinv gather) + gemm2 -> prescaled T2
    agg128_gemm2_kernel<<<node_blocks, 1024, 0, stream>>>((const uint2*)T1b, b1, dinv,
                                                          row_beg, row_end, csr, Wp2, T2b, N);
    // K4: agg64 + gemm3 -> prescaled T3
    agg64_gemm3_kernel<<<node_blocks, 1024, 0, stream>>>((const uint2*)T2b, b2, dinv,
                                                         row_beg, row_end, csr, Wp3, T3b, N);
    // K5: agg64 + head -> out
    agg64_head_kernel<<<node_blocks, 1024, 0, stream>>>((const uint2*)T3b, b3, dinv,
                                                        row_beg, row_end, csr,
                                                        pr, Wf0, bf0, Wf1, bf1, y, outp, N);
}

// Round 5
// 217.122 us; speedup vs baseline: 1.2723x; 1.0547x over previous
//
#include <hip/hip_runtime.h>
#include <hip/hip_bf16.h>
#include <hip/hip_fp16.h>
#include <math.h>

// ---------------------------------------------------------------------------
// SLADGNN round 17: 2-node-interleaved agg loops. r15/r16 showed aggs are
// wave-level latency-serial (3.4x occupancy -> only 1.8x speedup; TLP already
// maxed at 8 waves/SIMD). Double per-wave MLP: each wave aggregates 2 nodes
// concurrently (dup accumulators, back-to-back gathers, per-node masking).
// Fused kernels use 512-thread blocks (8 waves x 8 nodes = 4 pair-steps;
// 4 blocks/CU keeps 32 waves/CU, gentler VGPR occupancy cliff than 1024).
// ---------------------------------------------------------------------------

typedef __attribute__((ext_vector_type(8))) short short8;
typedef __attribute__((ext_vector_type(4))) float f32x4;

#define BKT_SHIFT 5
#define BKT_NODES 32
#define EPB 2048        // edges per sort_local block (391 blocks)
#define LCAP 1024       // per-bucket CSR slot capacity (mean 512, +22 sigma)
#define PREPN 28672     // prep_w elements
#define PREPB 112       // prep_w blocks

__device__ __forceinline__ short f2bs(float x) {
    __hip_bfloat16 b = __float2bfloat16(x);
    return *reinterpret_cast<short*>(&b);
}
__device__ __forceinline__ float bfround(float x) {
    return __bfloat162float(__float2bfloat16(x));
}
__device__ __forceinline__ unsigned packbf(float a, float b) {
    unsigned la = (unsigned)(unsigned short)f2bs(a);
    unsigned hb = (unsigned)(unsigned short)f2bs(b);
    return la | (hb << 16);
}

// ---- e5m2 helpers: e5m2 byte == high byte of f16 --------------------------
__device__ __forceinline__ unsigned short enc2_e5m2(float a, float b) {
    unsigned ua = __half_as_ushort(__float2half(a));
    unsigned ub = __half_as_ushort(__float2half(b));
    ua = (ua + 0x80u) >> 8;          // round-half-up on dropped byte
    ub = (ub + 0x80u) >> 8;
    return (unsigned short)((ua & 0xffu) | ((ub & 0xffu) << 8));
}
// bytes 0,1 of u -> half2
__device__ __forceinline__ __half2 dec2lo(unsigned u) {
    unsigned h = __builtin_amdgcn_perm(u, u, 0x010C000Cu);
    return *reinterpret_cast<__half2*>(&h);
}
// bytes 2,3 of u -> half2
__device__ __forceinline__ __half2 dec2hi(unsigned u) {
    unsigned h = __builtin_amdgcn_perm(u, u, 0x030C020Cu);
    return *reinterpret_cast<__half2*>(&h);
}
__device__ __forceinline__ __half2 h2shfl_xor(__half2 h, int m) {
    int i = *reinterpret_cast<int*>(&h);
    i = __shfl_xor(i, m, 64);
    return *reinterpret_cast<__half2*>(&i);
}
__device__ __forceinline__ __half2 h2shfl(__half2 h, int src) {
    int i = *reinterpret_cast<int*>(&h);
    i = __shfl(i, src, 64);
    return *reinterpret_cast<__half2*>(&i);
}

// Block-wide exclusive scan of arr[0..n) in LDS (256-thread blocks only).
__device__ __forceinline__ void block_excl_scan(int* __restrict__ arr, int n, int t) {
    __shared__ int wsums[4];
    int lane = t & 63, wv = t >> 6;
    int carry = 0;
    for (int c0 = 0; c0 < n; c0 += 256) {
        int i = c0 + t;
        int v = (i < n) ? arr[i] : 0;
        int orig = v;
#pragma unroll
        for (int off = 1; off < 64; off <<= 1) {
            int u = __shfl_up(v, off, 64);
            if (lane >= off) v += u;
        }
        if (lane == 63) wsums[wv] = v;
        __syncthreads();
        int w0 = wsums[0], w1 = wsums[1], w2 = wsums[2], w3 = wsums[3];
        int woff = (wv > 0 ? w0 : 0) + (wv > 1 ? w1 : 0) + (wv > 2 ? w2 : 0);
        int tot = w0 + w1 + w2 + w3;
        __syncthreads();
        if (i < n) arr[i] = carry + woff + (v - orig);
        carry += tot;
    }
}

// --------------------- K1: sort_local || prep W1/W2/W3 ---------------------

__global__ __launch_bounds__(256) void sort_local_kernel(const int* __restrict__ ei, int E,
                                                         int NB, int B,
                                                         int* __restrict__ glens,
                                                         int* __restrict__ gstart,
                                                         int* __restrict__ edge_sorted,
                                                         const float* __restrict__ W1,
                                                         const float* __restrict__ W2,
                                                         const float* __restrict__ W3,
                                                         __hip_bfloat16* __restrict__ Wp1,
                                                         __hip_bfloat16* __restrict__ Wp2,
                                                         __hip_bfloat16* __restrict__ Wp3) {
    int t = threadIdx.x;
    if ((int)blockIdx.x >= B) {
        int i = ((int)blockIdx.x - B) * 256 + t;
        if (i < 16384) {                      // W1: 128x128
            int k = i >> 7, n = i & 127;
            Wp1[(((k >> 3) * 128) + n) * 8 + (k & 7)] = __float2bfloat16(W1[i]);
        } else if (i < 24576) {               // W2: 128x64
            int j = i - 16384;
            int k = j >> 6, n = j & 63;
            Wp2[(((k >> 3) * 64) + n) * 8 + (k & 7)] = __float2bfloat16(W2[j]);
        } else if (i < PREPN) {               // W3: 64x64
            int j = i - 24576;
            int k = j >> 6, n = j & 63;
            Wp3[(((k >> 3) * 64) + n) * 8 + (k & 7)] = __float2bfloat16(W3[j]);
        }
        return;
    }
    extern __shared__ int lds[];
    int* hist  = lds;                 // NB
    int* lbase = lds + NB;            // NB
    int* sortd = lds + 2 * NB;        // EPB
    int blk = blockIdx.x;
    int e0 = blk * EPB;
    int cnt = E - e0;
    if (cnt > EPB) cnt = EPB;

    for (int i = t; i < NB; i += 256) hist[i] = 0;
    __syncthreads();
    for (int i = t; i < cnt; i += 256) {
        int dst = ei[E + e0 + i];
        atomicAdd(&hist[dst >> BKT_SHIFT], 1);
    }
    __syncthreads();
    for (int i = t; i < NB; i += 256) lbase[i] = hist[i];
    __syncthreads();
    block_excl_scan(lbase, NB, t);
    __syncthreads();
    for (int i = t; i < NB; i += 256) {
        glens[(size_t)blk * NB + i] = hist[i];
        gstart[(size_t)blk * NB + i] = lbase[i];
    }
    __syncthreads();
    for (int i = t; i < cnt; i += 256) {
        int src = ei[e0 + i];
        int dst = ei[E + e0 + i];
        int pos = atomicAdd(&lbase[dst >> BKT_SHIFT], 1);
        sortd[pos] = (src << BKT_SHIFT) | (dst & (BKT_NODES - 1));
    }
    __syncthreads();
    for (int i = t; i < cnt; i += 256) edge_sorted[e0 + i] = sortd[i];
}

// --------------------- K2: csr_build || gemm1 (disjoint block ranges) ------
// gemm1 stores T1 as e5m2 bytes (unscaled).

__global__ __launch_bounds__(256) void csr_gemm1_kernel(const int* __restrict__ edge_sorted,
                                                        const int* __restrict__ glens,
                                                        const int* __restrict__ gstart,
                                                        int NB, int B, int N,
                                                        int* __restrict__ row_beg,
                                                        int* __restrict__ row_end,
                                                        float* __restrict__ dinv,
                                                        int* __restrict__ csr,
                                                        const float* __restrict__ X,
                                                        const __hip_bfloat16* __restrict__ Wp1,
                                                        unsigned char* __restrict__ T1) {
    int t = threadIdx.x;
    if ((int)blockIdx.x >= NB) {
        int bid = (int)blockIdx.x - NB;
        int lane = t & 63;
        int wave = t >> 6;
        int q = lane >> 4, l16 = lane & 15;
        int rbase = bid * 64 + wave * 16;
        int row = rbase + l16;
        int rowc = row < N ? row : N - 1;
        f32x4 acc[8];
#pragma unroll
        for (int i = 0; i < 8; ++i) acc[i] = (f32x4){0.f, 0.f, 0.f, 0.f};
#pragma unroll
        for (int kt = 0; kt < 4; ++kt) {
            int k0 = kt * 32 + q * 8;
            const float* ap = X + (size_t)rowc * 128 + k0;
            float4 lo = *(const float4*)ap;
            float4 hi = *(const float4*)(ap + 4);
            short8 afrag;
            afrag[0] = f2bs(lo.x); afrag[1] = f2bs(lo.y);
            afrag[2] = f2bs(lo.z); afrag[3] = f2bs(lo.w);
            afrag[4] = f2bs(hi.x); afrag[5] = f2bs(hi.y);
            afrag[6] = f2bs(hi.z); afrag[7] = f2bs(hi.w);
            const short8* wrow = (const short8*)(Wp1 + (size_t)(kt * 4 + q) * 128 * 8);
#pragma unroll
            for (int tt = 0; tt < 8; ++tt) {
                short8 bfrag = wrow[tt * 16 + l16];
                acc[tt] = __builtin_amdgcn_mfma_f32_16x16x32_bf16(afrag, bfrag, acc[tt], 0, 0, 0);
            }
        }
        // epilogue: pair adjacent cols (l16, l16^1) via shfl, even lanes store u16
#pragma unroll
        for (int r = 0; r < 4; ++r) {
            int gr = rbase + q * 4 + r;
#pragma unroll
            for (int tt = 0; tt < 8; ++tt) {
                float v = acc[tt][r];
                float p = __shfl_xor(v, 1, 64);
                if (((l16 & 1) == 0) && gr < N)
                    *(unsigned short*)(T1 + (size_t)gr * 128 + tt * 16 + l16) = enc2_e5m2(v, p);
            }
        }
        return;
    }
    // ---- csr_build ----
    __shared__ int lruns[512];
    __shared__ int loffs[512];
    __shared__ int sdeg[BKT_NODES];
    __shared__ int scur[BKT_NODES];
    __shared__ int raw[LCAP];
    __shared__ int srt[LCAP];
    int b = blockIdx.x;

    for (int i = t; i < 512; i += 256) {
        int v = (i < B) ? glens[(size_t)i * NB + b] : 0;
        lruns[i] = v;
        loffs[i] = v;
    }
    if (t < BKT_NODES) sdeg[t] = 0;
    __syncthreads();
    block_excl_scan(loffs, B, t);
    __syncthreads();
    int cnt = loffs[B - 1] + lruns[B - 1];
    if (cnt > LCAP) cnt = LCAP;

    for (int r = t; r < B; r += 256) {
        int len = lruns[r];
        if (len) {
            int off = loffs[r];
            int st = r * EPB + gstart[(size_t)r * NB + b];
            for (int k = 0; k < len; ++k) {
                int p = off + k;
                if (p < LCAP) raw[p] = edge_sorted[st + k];
            }
        }
    }
    __syncthreads();
    for (int i = t; i < cnt; i += 256) atomicAdd(&sdeg[raw[i] & (BKT_NODES - 1)], 1);
    __syncthreads();
    int base = b * LCAP;
    if (t < BKT_NODES) {
        int ssum = 0;
        for (int i = 0; i < t; ++i) ssum += sdeg[i];
        scur[t] = ssum;
        int node = b * BKT_NODES + t;
        if (node < N) {
            row_beg[node] = base + ssum;
            row_end[node] = base + ssum + sdeg[t];
            dinv[node] = rsqrtf((float)(sdeg[t] + 1));   // +1 self loop
        }
    }
    __syncthreads();
    for (int i = t; i < cnt; i += 256) {
        int p = raw[i];
        int pos = atomicAdd(&scur[p & (BKT_NODES - 1)], 1);
        srt[pos] = p >> BKT_SHIFT;
    }
    __syncthreads();
    for (int i = t; i < cnt; i += 256) csr[base + i] = srt[i];
}

// --------------- K3: fused agg128 (unscaled T1, dinv gather) + gemm2 -------
// 512 threads: 8 waves x 8 nodes each, processed as 4 PAIRS (2 concurrent
// gather chains per wave). quarter-wave/edge per node. Results -> LDS bf16
// (row 136 shorts). GEMM: wave w -> row-tile w>>1, col-tiles (w&1)*2..+1.
__global__ __launch_bounds__(512) void agg128_gemm2_kernel(const uint2* __restrict__ tmp,
                                                           const float* __restrict__ bias,
                                                           const float* __restrict__ dinv,
                                                           const int* __restrict__ row_beg,
                                                           const int* __restrict__ row_end,
                                                           const int* __restrict__ csr_src,
                                                           const __hip_bfloat16* __restrict__ Wp,
                                                           unsigned char* __restrict__ C, int N) {
    __shared__ unsigned short Hs[64 * 136];
    int t = threadIdx.x;
    int wave = t >> 6, lane = t & 63;
    int q = lane >> 4, sub = lane & 15;
    int nbase = (int)blockIdx.x * 64;
    __half2 zero2 = __float2half2_rn(0.f);

#pragma unroll
    for (int p = 0; p < 4; ++p) {
        int nA = nbase + wave * 8 + 2 * p;
        int nB = nA + 1;
        bool okA = nA < N, okB = nB < N;
        float dviA = dinv[okA ? nA : 0];
        float dviB = dinv[okB ? nB : 0];
        __half2 a01 = zero2, a23 = zero2, a45 = zero2, a67 = zero2;
        __half2 b01 = zero2, b23 = zero2, b45 = zero2, b67 = zero2;
        if (q == 0) {
            if (okA) {
                uint2 sv = tmp[(size_t)nA * 16 + sub];
                __half2 d2 = __float2half2_rn(dviA);
                a01 = __hmul2(dec2lo(sv.x), d2);
                a23 = __hmul2(dec2hi(sv.x), d2);
                a45 = __hmul2(dec2lo(sv.y), d2);
                a67 = __hmul2(dec2hi(sv.y), d2);
            }
            if (okB) {
                uint2 sv = tmp[(size_t)nB * 16 + sub];
                __half2 d2 = __float2half2_rn(dviB);
                b01 = __hmul2(dec2lo(sv.x), d2);
                b23 = __hmul2(dec2hi(sv.x), d2);
                b45 = __hmul2(dec2lo(sv.y), d2);
                b67 = __hmul2(dec2hi(sv.y), d2);
            }
        }
        int jA = okA ? row_beg[nA] : 0, endA = okA ? row_end[nA] : 0;
        int jB = okB ? row_beg[nB] : 0, endB = okB ? row_end[nB] : 0;
        while (jA < endA || jB < endB) {
            int mA = endA - jA; mA = mA < 0 ? 0 : (mA > 64 ? 64 : mA);
            int mB = endB - jB; mB = mB < 0 ? 0 : (mB > 64 ? 64 : mB);
            int sA = 0; float fA = 0.f;
            if (lane < mA) { sA = csr_src[jA + lane]; fA = dinv[sA]; }
            int sB = 0; float fB = 0.f;
            if (lane < mB) { sB = csr_src[jB + lane]; fB = dinv[sB]; }
            __half2 hA = __float2half2_rn(fA);
            __half2 hB = __float2half2_rn(fB);
            int itA = (mA + 3) >> 2, itB = (mB + 3) >> 2;
            int it = itA > itB ? itA : itB;
            for (int k = 0; k < it; ++k) {
                int e = 4 * k + q;
                int eA = (e < mA) ? e : 0;
                int eB = (e < mB) ? e : 0;
                int skA = __shfl(sA, eA, 64);
                int skB = __shfl(sB, eB, 64);
                __half2 dA = h2shfl(hA, eA); if (e >= mA) dA = zero2;
                __half2 dB = h2shfl(hB, eB); if (e >= mB) dB = zero2;
                uint2 vA = tmp[(size_t)skA * 16 + sub];
                uint2 vB = tmp[(size_t)skB * 16 + sub];
                a01 = __hfma2(dec2lo(vA.x), dA, a01);
                a23 = __hfma2(dec2hi(vA.x), dA, a23);
                a45 = __hfma2(dec2lo(vA.y), dA, a45);
                a67 = __hfma2(dec2hi(vA.y), dA, a67);
                b01 = __hfma2(dec2lo(vB.x), dB, b01);
                b23 = __hfma2(dec2hi(vB.x), dB, b23);
                b45 = __hfma2(dec2lo(vB.y), dB, b45);
                b67 = __hfma2(dec2hi(vB.y), dB, b67);
            }
            jA += 64; jB += 64;
        }
#pragma unroll
        for (int off = 16; off <= 32; off <<= 1) {
            a01 = __hadd2(a01, h2shfl_xor(a01, off));
            a23 = __hadd2(a23, h2shfl_xor(a23, off));
            a45 = __hadd2(a45, h2shfl_xor(a45, off));
            a67 = __hadd2(a67, h2shfl_xor(a67, off));
            b01 = __hadd2(b01, h2shfl_xor(b01, off));
            b23 = __hadd2(b23, h2shfl_xor(b23, off));
            b45 = __hadd2(b45, h2shfl_xor(b45, off));
            b67 = __hadd2(b67, h2shfl_xor(b67, off));
        }
        if (q == 0 && okA) {
            float2 f01 = __half22float2(a01);
            float2 f23 = __half22float2(a23);
            float2 f45 = __half22float2(a45);
            float2 f67 = __half22float2(a67);
            float4 c0 = *(const float4*)&bias[sub * 8];
            float4 c1 = *(const float4*)&bias[sub * 8 + 4];
            uint4 o;
            o.x = packbf(fmaxf(dviA * f01.x + c0.x, 0.f), fmaxf(dviA * f01.y + c0.y, 0.f));
            o.y = packbf(fmaxf(dviA * f23.x + c0.z, 0.f), fmaxf(dviA * f23.y + c0.w, 0.f));
            o.z = packbf(fmaxf(dviA * f45.x + c1.x, 0.f), fmaxf(dviA * f45.y + c1.y, 0.f));
            o.w = packbf(fmaxf(dviA * f67.x + c1.z, 0.f), fmaxf(dviA * f67.y + c1.w, 0.f));
            *(uint4*)&Hs[(wave * 8 + 2 * p) * 136 + sub * 8] = o;
        }
        if (q == 0 && okB) {
            float2 f01 = __half22float2(b01);
            float2 f23 = __half22float2(b23);
            float2 f45 = __half22float2(b45);
            float2 f67 = __half22float2(b67);
            float4 c0 = *(const float4*)&bias[sub * 8];
            float4 c1 = *(const float4*)&bias[sub * 8 + 4];
            uint4 o;
            o.x = packbf(fmaxf(dviB * f01.x + c0.x, 0.f), fmaxf(dviB * f01.y + c0.y, 0.f));
            o.y = packbf(fmaxf(dviB * f23.x + c0.z, 0.f), fmaxf(dviB * f23.y + c0.w, 0.f));
            o.z = packbf(fmaxf(dviB * f45.x + c1.x, 0.f), fmaxf(dviB * f45.y + c1.y, 0.f));
            o.w = packbf(fmaxf(dviB * f67.x + c1.z, 0.f), fmaxf(dviB * f67.y + c1.w, 0.f));
            *(uint4*)&Hs[(wave * 8 + 2 * p + 1) * 136 + sub * 8] = o;
        }
    }
    __syncthreads();

    // ---- gemm2: DI=128 DO=64. wave -> row-tile w>>1, col-tiles (w&1)*2..+1
    int rt = wave >> 1, cb = (wave & 1) * 2;
    int l16 = lane & 15;
    int rbase = nbase + rt * 16;
    f32x4 acc[2];
    acc[0] = (f32x4){0.f, 0.f, 0.f, 0.f};
    acc[1] = (f32x4){0.f, 0.f, 0.f, 0.f};
#pragma unroll
    for (int kt = 0; kt < 4; ++kt) {
        short8 afrag = *(const short8*)&Hs[(rt * 16 + l16) * 136 + kt * 32 + q * 8];
        const short8* wrow = (const short8*)(Wp + (size_t)(kt * 4 + q) * 64 * 8);
#pragma unroll
        for (int c = 0; c < 2; ++c) {
            short8 bfrag = wrow[(cb + c) * 16 + l16];
            acc[c] = __builtin_amdgcn_mfma_f32_16x16x32_bf16(afrag, bfrag, acc[c], 0, 0, 0);
        }
    }
#pragma unroll
    for (int r = 0; r < 4; ++r) {
        int gr = rbase + q * 4 + r;
        float dv = dinv[gr < N ? gr : 0];
#pragma unroll
        for (int c = 0; c < 2; ++c) {
            float v = acc[c][r] * dv;
            float pp_ = __shfl_xor(v, 1, 64);
            if (((l16 & 1) == 0) && gr < N)
                *(unsigned short*)(C + (size_t)gr * 64 + (cb + c) * 16 + l16) = enc2_e5m2(v, pp_);
        }
    }
}

// --------------- K4: fused agg64 (prescaled T2) + gemm3 --------------------
// 512 threads: 8 waves x 8 nodes as 4 pairs, eighth-wave/edge. LDS row 72.
__global__ __launch_bounds__(512) void agg64_gemm3_kernel(const uint2* __restrict__ tmp,
                                                          const float* __restrict__ bias,
                                                          const float* __restrict__ dinv,
                                                          const int* __restrict__ row_beg,
                                                          const int* __restrict__ row_end,
                                                          const int* __restrict__ csr_src,
                                                          const __hip_bfloat16* __restrict__ Wp,
                                                          unsigned char* __restrict__ C, int N) {
    __shared__ unsigned short Hs[64 * 72];
    int t = threadIdx.x;
    int wave = t >> 6, lane = t & 63;
    int o8 = lane >> 3, sub8 = lane & 7;
    int nbase = (int)blockIdx.x * 64;
    __half2 zero2 = __float2half2_rn(0.f);
    __half2 one2 = __float2half2_rn(1.f);

#pragma unroll
    for (int p = 0; p < 4; ++p) {
        int nA = nbase + wave * 8 + 2 * p;
        int nB = nA + 1;
        bool okA = nA < N, okB = nB < N;
        float dviA = dinv[okA ? nA : 0];
        float dviB = dinv[okB ? nB : 0];
        __half2 a01 = zero2, a23 = zero2, a45 = zero2, a67 = zero2;
        __half2 b01 = zero2, b23 = zero2, b45 = zero2, b67 = zero2;
        if (o8 == 0) {
            if (okA) {
                uint2 sv = tmp[(size_t)nA * 8 + sub8];
                a01 = dec2lo(sv.x); a23 = dec2hi(sv.x);
                a45 = dec2lo(sv.y); a67 = dec2hi(sv.y);
            }
            if (okB) {
                uint2 sv = tmp[(size_t)nB * 8 + sub8];
                b01 = dec2lo(sv.x); b23 = dec2hi(sv.x);
                b45 = dec2lo(sv.y); b67 = dec2hi(sv.y);
            }
        }
        int jA = okA ? row_beg[nA] : 0, endA = okA ? row_end[nA] : 0;
        int jB = okB ? row_beg[nB] : 0, endB = okB ? row_end[nB] : 0;
        while (jA < endA || jB < endB) {
            int mA = endA - jA; mA = mA < 0 ? 0 : (mA > 64 ? 64 : mA);
            int mB = endB - jB; mB = mB < 0 ? 0 : (mB > 64 ? 64 : mB);
            int sA = (lane < mA) ? csr_src[jA + lane] : 0;
            int sB = (lane < mB) ? csr_src[jB + lane] : 0;
            int itA = (mA + 7) >> 3, itB = (mB + 7) >> 3;
            int it = itA > itB ? itA : itB;
            for (int k = 0; k < it; ++k) {
                int e = 8 * k + o8;
                int eA = (e < mA) ? e : 0;
                int eB = (e < mB) ? e : 0;
                int skA = __shfl(sA, eA, 64);
                int skB = __shfl(sB, eB, 64);
                __half2 dA = (e < mA) ? one2 : zero2;
                __half2 dB = (e < mB) ? one2 : zero2;
                uint2 vA = tmp[(size_t)skA * 8 + sub8];
                uint2 vB = tmp[(size_t)skB * 8 + sub8];
                a01 = __hfma2(dec2lo(vA.x), dA, a01);
                a23 = __hfma2(dec2hi(vA.x), dA, a23);
                a45 = __hfma2(dec2lo(vA.y), dA, a45);
                a67 = __hfma2(dec2hi(vA.y), dA, a67);
                b01 = __hfma2(dec2lo(vB.x), dB, b01);
                b23 = __hfma2(dec2hi(vB.x), dB, b23);
                b45 = __hfma2(dec2lo(vB.y), dB, b45);
                b67 = __hfma2(dec2hi(vB.y), dB, b67);
            }
            jA += 64; jB += 64;
        }
#pragma unroll
        for (int off = 8; off <= 32; off <<= 1) {
            a01 = __hadd2(a01, h2shfl_xor(a01, off));
            a23 = __hadd2(a23, h2shfl_xor(a23, off));
            a45 = __hadd2(a45, h2shfl_xor(a45, off));
            a67 = __hadd2(a67, h2shfl_xor(a67, off));
            b01 = __hadd2(b01, h2shfl_xor(b01, off));
            b23 = __hadd2(b23, h2shfl_xor(b23, off));
            b45 = __hadd2(b45, h2shfl_xor(b45, off));
            b67 = __hadd2(b67, h2shfl_xor(b67, off));
        }
        if (o8 == 0 && okA) {
            float2 f01 = __half22float2(a01);
            float2 f23 = __half22float2(a23);
            float2 f45 = __half22float2(a45);
            float2 f67 = __half22float2(a67);
            float4 c0 = *(const float4*)&bias[sub8 * 8];
            float4 c1 = *(const float4*)&bias[sub8 * 8 + 4];
            uint4 o;
            o.x = packbf(fmaxf(dviA * f01.x + c0.x, 0.f), fmaxf(dviA * f01.y + c0.y, 0.f));
            o.y = packbf(fmaxf(dviA * f23.x + c0.z, 0.f), fmaxf(dviA * f23.y + c0.w, 0.f));
            o.z = packbf(fmaxf(dviA * f45.x + c1.x, 0.f), fmaxf(dviA * f45.y + c1.y, 0.f));
            o.w = packbf(fmaxf(dviA * f67.x + c1.z, 0.f), fmaxf(dviA * f67.y + c1.w, 0.f));
            *(uint4*)&Hs[(wave * 8 + 2 * p) * 72 + sub8 * 8] = o;
        }
        if (o8 == 0 && okB) {
            float2 f01 = __half22float2(b01);
            float2 f23 = __half22float2(b23);
            float2 f45 = __half22float2(b45);
            float2 f67 = __half22float2(b67);
            float4 c0 = *(const float4*)&bias[sub8 * 8];
            float4 c1 = *(const float4*)&bias[sub8 * 8 + 4];
            uint4 o;
            o.x = packbf(fmaxf(dviB * f01.x + c0.x, 0.f), fmaxf(dviB * f01.y + c0.y, 0.f));
            o.y = packbf(fmaxf(dviB * f23.x + c0.z, 0.f), fmaxf(dviB * f23.y + c0.w, 0.f));
            o.z = packbf(fmaxf(dviB * f45.x + c1.x, 0.f), fmaxf(dviB * f45.y + c1.y, 0.f));
            o.w = packbf(fmaxf(dviB * f67.x + c1.z, 0.f), fmaxf(dviB * f67.y + c1.w, 0.f));
            *(uint4*)&Hs[(wave * 8 + 2 * p + 1) * 72 + sub8 * 8] = o;
        }
    }
    __syncthreads();

    // ---- gemm3: DI=64 DO=64. wave -> row-tile w>>1, col-tiles (w&1)*2..+1
    int rt = wave >> 1, cb = (wave & 1) * 2;
    int q = lane >> 4, l16 = lane & 15;
    int rbase = nbase + rt * 16;
    f32x4 acc[2];
    acc[0] = (f32x4){0.f, 0.f, 0.f, 0.f};
    acc[1] = (f32x4){0.f, 0.f, 0.f, 0.f};
#pragma unroll
    for (int kt = 0; kt < 2; ++kt) {
        short8 afrag = *(const short8*)&Hs[(rt * 16 + l16) * 72 + kt * 32 + q * 8];
        const short8* wrow = (const short8*)(Wp + (size_t)(kt * 4 + q) * 64 * 8);
#pragma unroll
        for (int c = 0; c < 2; ++c) {
            short8 bfrag = wrow[(cb + c) * 16 + l16];
            acc[c] = __builtin_amdgcn_mfma_f32_16x16x32_bf16(afrag, bfrag, acc[c], 0, 0, 0);
        }
    }
#pragma unroll
    for (int r = 0; r < 4; ++r) {
        int gr = rbase + q * 4 + r;
        float dv = dinv[gr < N ? gr : 0];
#pragma unroll
        for (int c = 0; c < 2; ++c) {
            float v = acc[c][r] * dv;
            float pp_ = __shfl_xor(v, 1, 64);
            if (((l16 & 1) == 0) && gr < N)
                *(unsigned short*)(C + (size_t)gr * 64 + (cb + c) * 16 + l16) = enc2_e5m2(v, pp_);
        }
    }
}

// --------------- K5: fused agg64 (prescaled T3) + head ---------------------
// 512 threads: 8 waves x 8 nodes as 4 pairs; head stages gated to t<256/64.
__global__ __launch_bounds__(512) void agg64_head_kernel(const uint2* __restrict__ tmp,
                                                         const float* __restrict__ bias,
                                                         const float* __restrict__ dinv,
                                                         const int* __restrict__ row_beg,
                                                         const int* __restrict__ row_end,
                                                         const int* __restrict__ csr_src,
                                                         const float* __restrict__ protos,
                                                         const float* __restrict__ Wf0,
                                                         const float* __restrict__ bf0,
                                                         const float* __restrict__ Wf1,
                                                         const float* __restrict__ bf1,
                                                         const int* __restrict__ y,
                                                         float* __restrict__ out, int N) {
    __shared__ float Hl[64 * 65];
    __shared__ float Pl[16 * 65];
    __shared__ float hh[64];
    __shared__ float pp[16];
    __shared__ float sim[64 * 17];
    __shared__ float Wf0l[128];
    __shared__ float bf0l[8];
    __shared__ float Wf1l[8];
    __shared__ float bf1l;
    int t = threadIdx.x;
    int wave = t >> 6, lane = t & 63;
    int o8 = lane >> 3, sub8 = lane & 7;
    int n0 = (int)blockIdx.x * 64;

    // prefetch head constants
    for (int idx = t; idx < 16 * 64; idx += 512) {
        int r = idx >> 6, c = idx & 63;
        Pl[r * 65 + c] = protos[idx];
    }
    if (t < 128) Wf0l[t] = Wf0[t];
    if (t < 8) { bf0l[t] = bf0[t]; Wf1l[t] = Wf1[t]; }
    if (t == 0) bf1l = bf1[0];

    __half2 zero2 = __float2half2_rn(0.f);
    __half2 one2 = __float2half2_rn(1.f);
#pragma unroll
    for (int p = 0; p < 4; ++p) {
        int nA = n0 + wave * 8 + 2 * p;
        int nB = nA + 1;
        bool okA = nA < N, okB = nB < N;
        float dviA = dinv[okA ? nA : 0];
        float dviB = dinv[okB ? nB : 0];
        __half2 a01 = zero2, a23 = zero2, a45 = zero2, a67 = zero2;
        __half2 b01 = zero2, b23 = zero2, b45 = zero2, b67 = zero2;
        if (o8 == 0) {
            if (okA) {
                uint2 sv = tmp[(size_t)nA * 8 + sub8];
                a01 = dec2lo(sv.x); a23 = dec2hi(sv.x);
                a45 = dec2lo(sv.y); a67 = dec2hi(sv.y);
            }
            if (okB) {
                uint2 sv = tmp[(size_t)nB * 8 + sub8];
                b01 = dec2lo(sv.x); b23 = dec2hi(sv.x);
                b45 = dec2lo(sv.y); b67 = dec2hi(sv.y);
            }
        }
        int jA = okA ? row_beg[nA] : 0, endA = okA ? row_end[nA] : 0;
        int jB = okB ? row_beg[nB] : 0, endB = okB ? row_end[nB] : 0;
        while (jA < endA || jB < endB) {
            int mA = endA - jA; mA = mA < 0 ? 0 : (mA > 64 ? 64 : mA);
            int mB = endB - jB; mB = mB < 0 ? 0 : (mB > 64 ? 64 : mB);
            int sA = (lane < mA) ? csr_src[jA + lane] : 0;
            int sB = (lane < mB) ? csr_src[jB + lane] : 0;
            int itA = (mA + 7) >> 3, itB = (mB + 7) >> 3;
            int it = itA > itB ? itA : itB;
            for (int k = 0; k < it; ++k) {
                int e = 8 * k + o8;
                int eA = (e < mA) ? e : 0;
                int eB = (e < mB) ? e : 0;
                int skA = __shfl(sA, eA, 64);
                int skB = __shfl(sB, eB, 64);
                __half2 dA = (e < mA) ? one2 : zero2;
                __half2 dB = (e < mB) ? one2 : zero2;
                uint2 vA = tmp[(size_t)skA * 8 + sub8];
                uint2 vB = tmp[(size_t)skB * 8 + sub8];
                a01 = __hfma2(dec2lo(vA.x), dA, a01);
                a23 = __hfma2(dec2hi(vA.x), dA, a23);
                a45 = __hfma2(dec2lo(vA.y), dA, a45);
                a67 = __hfma2(dec2hi(vA.y), dA, a67);
                b01 = __hfma2(dec2lo(vB.x), dB, b01);
                b23 = __hfma2(dec2hi(vB.x), dB, b23);
                b45 = __hfma2(dec2lo(vB.y), dB, b45);
                b67 = __hfma2(dec2hi(vB.y), dB, b67);
            }
            jA += 64; jB += 64;
        }
#pragma unroll
        for (int off = 8; off <= 32; off <<= 1) {
            a01 = __hadd2(a01, h2shfl_xor(a01, off));
            a23 = __hadd2(a23, h2shfl_xor(a23, off));
            a45 = __hadd2(a45, h2shfl_xor(a45, off));
            a67 = __hadd2(a67, h2shfl_xor(a67, off));
            b01 = __hadd2(b01, h2shfl_xor(b01, off));
            b23 = __hadd2(b23, h2shfl_xor(b23, off));
            b45 = __hadd2(b45, h2shfl_xor(b45, off));
            b67 = __hadd2(b67, h2shfl_xor(b67, off));
        }
        if (o8 == 0 && okA) {
            float2 f01 = __half22float2(a01);
            float2 f23 = __half22float2(a23);
            float2 f45 = __half22float2(a45);
            float2 f67 = __half22float2(a67);
            float4 c0 = *(const float4*)&bias[sub8 * 8];
            float4 c1 = *(const float4*)&bias[sub8 * 8 + 4];
            float* hrow = &Hl[(wave * 8 + 2 * p) * 65 + sub8 * 8];
            hrow[0] = bfround(fmaxf(dviA * f01.x + c0.x, 0.f));
            hrow[1] = bfround(fmaxf(dviA * f01.y + c0.y, 0.f));
            hrow[2] = bfround(fmaxf(dviA * f23.x + c0.z, 0.f));
            hrow[3] = bfround(fmaxf(dviA * f23.y + c0.w, 0.f));
            hrow[4] = bfround(fmaxf(dviA * f45.x + c1.x, 0.f));
            hrow[5] = bfround(fmaxf(dviA * f45.y + c1.y, 0.f));
            hrow[6] = bfround(fmaxf(dviA * f67.x + c1.z, 0.f));
            hrow[7] = bfround(fmaxf(dviA * f67.y + c1.w, 0.f));
        }
        if (o8 == 0 && okB) {
            float2 f01 = __half22float2(b01);
            float2 f23 = __half22float2(b23);
            float2 f45 = __half22float2(b45);
            float2 f67 = __half22float2(b67);
            float4 c0 = *(const float4*)&bias[sub8 * 8];
            float4 c1 = *(const float4*)&bias[sub8 * 8 + 4];
            float* hrow = &Hl[(wave * 8 + 2 * p + 1) * 65 + sub8 * 8];
            hrow[0] = bfround(fmaxf(dviB * f01.x + c0.x, 0.f));
            hrow[1] = bfround(fmaxf(dviB * f01.y + c0.y, 0.f));
            hrow[2] = bfround(fmaxf(dviB * f23.x + c0.z, 0.f));
            hrow[3] = bfround(fmaxf(dviB * f23.y + c0.w, 0.f));
            hrow[4] = bfround(fmaxf(dviB * f45.x + c1.x, 0.f));
            hrow[5] = bfround(fmaxf(dviB * f45.y + c1.y, 0.f));
            hrow[6] = bfround(fmaxf(dviB * f67.x + c1.z, 0.f));
            hrow[7] = bfround(fmaxf(dviB * f67.y + c1.w, 0.f));
        }
    }
    __syncthreads();

    if (t < 64) {
        float s = 0.0f;
        for (int k = 0; k < 64; ++k) { float v = Hl[t * 65 + k]; s += v * v; }
        hh[t] = s;
    } else if (t < 80) {
        int p = t - 64;
        float s = 0.0f;
        for (int k = 0; k < 64; ++k) { float v = Pl[p * 65 + k]; s += v * v; }
        pp[p] = s;
    }
    __syncthreads();

    if (t < 256) {
        int node = t & 63;
        int p4 = (t >> 6) * 4;
        float d0 = 0, d1 = 0, d2 = 0, d3 = 0;
        for (int k = 0; k < 64; ++k) {
            float hv = Hl[node * 65 + k];
            d0 += hv * Pl[(p4 + 0) * 65 + k];
            d1 += hv * Pl[(p4 + 1) * 65 + k];
            d2 += hv * Pl[(p4 + 2) * 65 + k];
            d3 += hv * Pl[(p4 + 3) * 65 + k];
        }
        float hhv = hh[node];
        float dd[4] = {d0, d1, d2, d3};
#pragma unroll
        for (int j = 0; j < 4; ++j) {
            float qd = hhv + pp[p4 + j] - 2.0f * dd[j];
            qd = qd > 0.0f ? qd : 0.0f;
            sim[node * 17 + p4 + j] = logf((qd + 1.0f) / (qd + 1e-4f));
        }
    }
    __syncthreads();

    if (t < 64) {
        int g = n0 + t;
        if (g < N) {
            float zacc = bf1l;
#pragma unroll
            for (int o = 0; o < 8; ++o) {
                float s = bf0l[o];
#pragma unroll
                for (int i2 = 0; i2 < 16; ++i2) s += sim[t * 17 + i2] * Wf0l[i2 * 8 + o];
                float gz = 0.5f * s * (1.0f + erff(s * 0.70710678118654752f));
                zacc += gz * Wf1l[o];
            }
            out[g] = 1.0f / (1.0f + expf(-zacc));
        }
    } else if (t < 128) {
        int g = n0 + (t - 64);
        if (g < N) out[N + g] = (float)y[g];
    }
}

// ---------------------------------------------------------------------------

extern "C" void kernel_launch(void* const* d_in, const int* in_sizes, int n_in,
                              void* d_out, int out_size, void* d_ws, size_t ws_size,
                              hipStream_t stream) {
    const float* x   = (const float*)d_in[0];
    const int*   ei  = (const int*)d_in[1];
    const int*   y   = (const int*)d_in[2];
    const float* W1  = (const float*)d_in[3];
    const float* b1  = (const float*)d_in[4];
    const float* W2  = (const float*)d_in[5];
    const float* b2  = (const float*)d_in[6];
    const float* W3  = (const float*)d_in[7];
    const float* b3  = (const float*)d_in[8];
    const float* pr  = (const float*)d_in[9];
    const float* Wf0 = (const float*)d_in[10];
    const float* bf0 = (const float*)d_in[11];
    const float* Wf1 = (const float*)d_in[12];
    const float* bf1 = (const float*)d_in[13];
    float* outp = (float*)d_out;

    const int N = in_sizes[2];       // 50000
    const int E = in_sizes[1] / 2;   // 800000
    const int NB = (N + BKT_NODES - 1) / BKT_NODES;   // 1563
    const int B = (E + EPB - 1) / EPB;                // 391 (<=512)

    char* w = (char*)d_ws;
    auto carve = [&](size_t bytes) {
        char* p = w;
        w += (bytes + 511) & ~(size_t)511;
        return p;
    };
    int*   glens   = (int*)carve((size_t)B * NB * 4);
    int*   gstart  = (int*)carve((size_t)B * NB * 4);
    int*   esort   = (int*)carve((size_t)B * EPB * 4);
    int*   row_beg = (int*)carve((size_t)N * 4);
    int*   row_end = (int*)carve((size_t)N * 4);
    float* dinv    = (float*)carve((size_t)N * 4);
    int*   csr     = (int*)carve((size_t)NB * LCAP * 4);
    __hip_bfloat16* Wp1 = (__hip_bfloat16*)carve(16384 * 2);
    __hip_bfloat16* Wp2 = (__hip_bfloat16*)carve(8192 * 2);
    __hip_bfloat16* Wp3 = (__hip_bfloat16*)carve(4096 * 2);
    unsigned char* T1b = (unsigned char*)carve((size_t)N * 128);   // e5m2
    unsigned char* T2b = (unsigned char*)carve((size_t)N * 64);    // e5m2
    unsigned char* T3b = (unsigned char*)carve((size_t)N * 64);    // e5m2

    size_t sort_lds = (size_t)(2 * NB + EPB) * 4;   // ~20.7 KB
    const int gemm1_blocks = (N + 63) / 64;          // 782
    const int node_blocks = (N + 63) / 64;           // 782

    // K1: bin+sort edges || pack weights
    sort_local_kernel<<<B + PREPB, 256, sort_lds, stream>>>(ei, E, NB, B, glens, gstart, esort,
                                                            W1, W2, W3, Wp1, Wp2, Wp3);
    // K2: CSR build || gemm1 (unscaled T1 -> fp8)
    csr_gemm1_kernel<<<NB + gemm1_blocks, 256, 0, stream>>>(esort, glens, gstart, NB, B, N,
                                                            row_beg, row_end, dinv, csr,
                                                            x, Wp1, T1b);
    // K3: agg128 (dinv gather, 2-node interleave) + gemm2 -> prescaled T2
    agg128_gemm2_kernel<<<node_blocks, 512, 0, stream>>>((const uint2*)T1b, b1, dinv,
                                                         row_beg, row_end, csr, Wp2, T2b, N);
    // K4: agg64 (2-node interleave) + gemm3 -> prescaled T3
    agg64_gemm3_kernel<<<node_blocks, 512, 0, stream>>>((const uint2*)T2b, b2, dinv,
                                                        row_beg, row_end, csr, Wp3, T3b, N);
    // K5: agg64 (2-node interleave) + head -> out
    agg64_head_kernel<<<node_blocks, 512, 0, stream>>>((const uint2*)T3b, b3, dinv,
                                                       row_beg, row_end, csr,
                                                       pr, Wf0, bf0, Wf1, bf1, y, outp, N);
}

// Round 6
// 210.680 us; speedup vs baseline: 1.3112x; 1.0306x over previous
//
#include <hip/hip_runtime.h>
#include <hip/hip_bf16.h>
#include <hip/hip_fp16.h>
#include <math.h>

// ---------------------------------------------------------------------------
// SLADGNN round 18: deepen per-wave MLP in agg loops. r17 (2-node interleave)
// gave -12us, confirming latency-bound gathers. Now unroll the inner k-loop
// x2: each body issues 4 independent gathers (A-k, B-k, A-k+1, B-k+1) before
// the dependent fmas -> ~4 loads in flight/wave (was ~2), no new persistent
// accumulators (VGPR stays <= ~64 for full 8 waves/SIMD occupancy).
// ---------------------------------------------------------------------------

typedef __attribute__((ext_vector_type(8))) short short8;
typedef __attribute__((ext_vector_type(4))) float f32x4;

#define BKT_SHIFT 5
#define BKT_NODES 32
#define EPB 2048        // edges per sort_local block (391 blocks)
#define LCAP 1024       // per-bucket CSR slot capacity (mean 512, +22 sigma)
#define PREPN 28672     // prep_w elements
#define PREPB 112       // prep_w blocks

__device__ __forceinline__ short f2bs(float x) {
    __hip_bfloat16 b = __float2bfloat16(x);
    return *reinterpret_cast<short*>(&b);
}
__device__ __forceinline__ float bfround(float x) {
    return __bfloat162float(__float2bfloat16(x));
}
__device__ __forceinline__ unsigned packbf(float a, float b) {
    unsigned la = (unsigned)(unsigned short)f2bs(a);
    unsigned hb = (unsigned)(unsigned short)f2bs(b);
    return la | (hb << 16);
}

// ---- e5m2 helpers: e5m2 byte == high byte of f16 --------------------------
__device__ __forceinline__ unsigned short enc2_e5m2(float a, float b) {
    unsigned ua = __half_as_ushort(__float2half(a));
    unsigned ub = __half_as_ushort(__float2half(b));
    ua = (ua + 0x80u) >> 8;          // round-half-up on dropped byte
    ub = (ub + 0x80u) >> 8;
    return (unsigned short)((ua & 0xffu) | ((ub & 0xffu) << 8));
}
// bytes 0,1 of u -> half2
__device__ __forceinline__ __half2 dec2lo(unsigned u) {
    unsigned h = __builtin_amdgcn_perm(u, u, 0x010C000Cu);
    return *reinterpret_cast<__half2*>(&h);
}
// bytes 2,3 of u -> half2
__device__ __forceinline__ __half2 dec2hi(unsigned u) {
    unsigned h = __builtin_amdgcn_perm(u, u, 0x030C020Cu);
    return *reinterpret_cast<__half2*>(&h);
}
__device__ __forceinline__ __half2 h2shfl_xor(__half2 h, int m) {
    int i = *reinterpret_cast<int*>(&h);
    i = __shfl_xor(i, m, 64);
    return *reinterpret_cast<__half2*>(&i);
}
__device__ __forceinline__ __half2 h2shfl(__half2 h, int src) {
    int i = *reinterpret_cast<int*>(&h);
    i = __shfl(i, src, 64);
    return *reinterpret_cast<__half2*>(&i);
}

// Block-wide exclusive scan of arr[0..n) in LDS (256-thread blocks only).
__device__ __forceinline__ void block_excl_scan(int* __restrict__ arr, int n, int t) {
    __shared__ int wsums[4];
    int lane = t & 63, wv = t >> 6;
    int carry = 0;
    for (int c0 = 0; c0 < n; c0 += 256) {
        int i = c0 + t;
        int v = (i < n) ? arr[i] : 0;
        int orig = v;
#pragma unroll
        for (int off = 1; off < 64; off <<= 1) {
            int u = __shfl_up(v, off, 64);
            if (lane >= off) v += u;
        }
        if (lane == 63) wsums[wv] = v;
        __syncthreads();
        int w0 = wsums[0], w1 = wsums[1], w2 = wsums[2], w3 = wsums[3];
        int woff = (wv > 0 ? w0 : 0) + (wv > 1 ? w1 : 0) + (wv > 2 ? w2 : 0);
        int tot = w0 + w1 + w2 + w3;
        __syncthreads();
        if (i < n) arr[i] = carry + woff + (v - orig);
        carry += tot;
    }
}

// --------------------- K1: sort_local || prep W1/W2/W3 ---------------------

__global__ __launch_bounds__(256) void sort_local_kernel(const int* __restrict__ ei, int E,
                                                         int NB, int B,
                                                         int* __restrict__ glens,
                                                         int* __restrict__ gstart,
                                                         int* __restrict__ edge_sorted,
                                                         const float* __restrict__ W1,
                                                         const float* __restrict__ W2,
                                                         const float* __restrict__ W3,
                                                         __hip_bfloat16* __restrict__ Wp1,
                                                         __hip_bfloat16* __restrict__ Wp2,
                                                         __hip_bfloat16* __restrict__ Wp3) {
    int t = threadIdx.x;
    if ((int)blockIdx.x >= B) {
        int i = ((int)blockIdx.x - B) * 256 + t;
        if (i < 16384) {                      // W1: 128x128
            int k = i >> 7, n = i & 127;
            Wp1[(((k >> 3) * 128) + n) * 8 + (k & 7)] = __float2bfloat16(W1[i]);
        } else if (i < 24576) {               // W2: 128x64
            int j = i - 16384;
            int k = j >> 6, n = j & 63;
            Wp2[(((k >> 3) * 64) + n) * 8 + (k & 7)] = __float2bfloat16(W2[j]);
        } else if (i < PREPN) {               // W3: 64x64
            int j = i - 24576;
            int k = j >> 6, n = j & 63;
            Wp3[(((k >> 3) * 64) + n) * 8 + (k & 7)] = __float2bfloat16(W3[j]);
        }
        return;
    }
    extern __shared__ int lds[];
    int* hist  = lds;                 // NB
    int* lbase = lds + NB;            // NB
    int* sortd = lds + 2 * NB;        // EPB
    int blk = blockIdx.x;
    int e0 = blk * EPB;
    int cnt = E - e0;
    if (cnt > EPB) cnt = EPB;

    for (int i = t; i < NB; i += 256) hist[i] = 0;
    __syncthreads();
    for (int i = t; i < cnt; i += 256) {
        int dst = ei[E + e0 + i];
        atomicAdd(&hist[dst >> BKT_SHIFT], 1);
    }
    __syncthreads();
    for (int i = t; i < NB; i += 256) lbase[i] = hist[i];
    __syncthreads();
    block_excl_scan(lbase, NB, t);
    __syncthreads();
    for (int i = t; i < NB; i += 256) {
        glens[(size_t)blk * NB + i] = hist[i];
        gstart[(size_t)blk * NB + i] = lbase[i];
    }
    __syncthreads();
    for (int i = t; i < cnt; i += 256) {
        int src = ei[e0 + i];
        int dst = ei[E + e0 + i];
        int pos = atomicAdd(&lbase[dst >> BKT_SHIFT], 1);
        sortd[pos] = (src << BKT_SHIFT) | (dst & (BKT_NODES - 1));
    }
    __syncthreads();
    for (int i = t; i < cnt; i += 256) edge_sorted[e0 + i] = sortd[i];
}

// --------------------- K2: csr_build || gemm1 (disjoint block ranges) ------
// gemm1 stores T1 as e5m2 bytes (unscaled).

__global__ __launch_bounds__(256) void csr_gemm1_kernel(const int* __restrict__ edge_sorted,
                                                        const int* __restrict__ glens,
                                                        const int* __restrict__ gstart,
                                                        int NB, int B, int N,
                                                        int* __restrict__ row_beg,
                                                        int* __restrict__ row_end,
                                                        float* __restrict__ dinv,
                                                        int* __restrict__ csr,
                                                        const float* __restrict__ X,
                                                        const __hip_bfloat16* __restrict__ Wp1,
                                                        unsigned char* __restrict__ T1) {
    int t = threadIdx.x;
    if ((int)blockIdx.x >= NB) {
        int bid = (int)blockIdx.x - NB;
        int lane = t & 63;
        int wave = t >> 6;
        int q = lane >> 4, l16 = lane & 15;
        int rbase = bid * 64 + wave * 16;
        int row = rbase + l16;
        int rowc = row < N ? row : N - 1;
        f32x4 acc[8];
#pragma unroll
        for (int i = 0; i < 8; ++i) acc[i] = (f32x4){0.f, 0.f, 0.f, 0.f};
#pragma unroll
        for (int kt = 0; kt < 4; ++kt) {
            int k0 = kt * 32 + q * 8;
            const float* ap = X + (size_t)rowc * 128 + k0;
            float4 lo = *(const float4*)ap;
            float4 hi = *(const float4*)(ap + 4);
            short8 afrag;
            afrag[0] = f2bs(lo.x); afrag[1] = f2bs(lo.y);
            afrag[2] = f2bs(lo.z); afrag[3] = f2bs(lo.w);
            afrag[4] = f2bs(hi.x); afrag[5] = f2bs(hi.y);
            afrag[6] = f2bs(hi.z); afrag[7] = f2bs(hi.w);
            const short8* wrow = (const short8*)(Wp1 + (size_t)(kt * 4 + q) * 128 * 8);
#pragma unroll
            for (int tt = 0; tt < 8; ++tt) {
                short8 bfrag = wrow[tt * 16 + l16];
                acc[tt] = __builtin_amdgcn_mfma_f32_16x16x32_bf16(afrag, bfrag, acc[tt], 0, 0, 0);
            }
        }
        // epilogue: pair adjacent cols (l16, l16^1) via shfl, even lanes store u16
#pragma unroll
        for (int r = 0; r < 4; ++r) {
            int gr = rbase + q * 4 + r;
#pragma unroll
            for (int tt = 0; tt < 8; ++tt) {
                float v = acc[tt][r];
                float p = __shfl_xor(v, 1, 64);
                if (((l16 & 1) == 0) && gr < N)
                    *(unsigned short*)(T1 + (size_t)gr * 128 + tt * 16 + l16) = enc2_e5m2(v, p);
            }
        }
        return;
    }
    // ---- csr_build ----
    __shared__ int lruns[512];
    __shared__ int loffs[512];
    __shared__ int sdeg[BKT_NODES];
    __shared__ int scur[BKT_NODES];
    __shared__ int raw[LCAP];
    __shared__ int srt[LCAP];
    int b = blockIdx.x;

    for (int i = t; i < 512; i += 256) {
        int v = (i < B) ? glens[(size_t)i * NB + b] : 0;
        lruns[i] = v;
        loffs[i] = v;
    }
    if (t < BKT_NODES) sdeg[t] = 0;
    __syncthreads();
    block_excl_scan(loffs, B, t);
    __syncthreads();
    int cnt = loffs[B - 1] + lruns[B - 1];
    if (cnt > LCAP) cnt = LCAP;

    for (int r = t; r < B; r += 256) {
        int len = lruns[r];
        if (len) {
            int off = loffs[r];
            int st = r * EPB + gstart[(size_t)r * NB + b];
            for (int k = 0; k < len; ++k) {
                int p = off + k;
                if (p < LCAP) raw[p] = edge_sorted[st + k];
            }
        }
    }
    __syncthreads();
    for (int i = t; i < cnt; i += 256) atomicAdd(&sdeg[raw[i] & (BKT_NODES - 1)], 1);
    __syncthreads();
    int base = b * LCAP;
    if (t < BKT_NODES) {
        int ssum = 0;
        for (int i = 0; i < t; ++i) ssum += sdeg[i];
        scur[t] = ssum;
        int node = b * BKT_NODES + t;
        if (node < N) {
            row_beg[node] = base + ssum;
            row_end[node] = base + ssum + sdeg[t];
            dinv[node] = rsqrtf((float)(sdeg[t] + 1));   // +1 self loop
        }
    }
    __syncthreads();
    for (int i = t; i < cnt; i += 256) {
        int p = raw[i];
        int pos = atomicAdd(&scur[p & (BKT_NODES - 1)], 1);
        srt[pos] = p >> BKT_SHIFT;
    }
    __syncthreads();
    for (int i = t; i < cnt; i += 256) csr[base + i] = srt[i];
}

// --------------- K3: fused agg128 (unscaled T1, dinv gather) + gemm2 -------
// 512 threads: 8 waves x 8 nodes as 4 pairs; inner k-loop unrolled x2
// (4 gathers in flight). quarter-wave/edge.
__global__ __launch_bounds__(512) void agg128_gemm2_kernel(const uint2* __restrict__ tmp,
                                                           const float* __restrict__ bias,
                                                           const float* __restrict__ dinv,
                                                           const int* __restrict__ row_beg,
                                                           const int* __restrict__ row_end,
                                                           const int* __restrict__ csr_src,
                                                           const __hip_bfloat16* __restrict__ Wp,
                                                           unsigned char* __restrict__ C, int N) {
    __shared__ unsigned short Hs[64 * 136];
    int t = threadIdx.x;
    int wave = t >> 6, lane = t & 63;
    int q = lane >> 4, sub = lane & 15;
    int nbase = (int)blockIdx.x * 64;
    __half2 zero2 = __float2half2_rn(0.f);

#pragma unroll
    for (int p = 0; p < 4; ++p) {
        int nA = nbase + wave * 8 + 2 * p;
        int nB = nA + 1;
        bool okA = nA < N, okB = nB < N;
        float dviA = dinv[okA ? nA : 0];
        float dviB = dinv[okB ? nB : 0];
        __half2 a01 = zero2, a23 = zero2, a45 = zero2, a67 = zero2;
        __half2 b01 = zero2, b23 = zero2, b45 = zero2, b67 = zero2;
        if (q == 0) {
            if (okA) {
                uint2 sv = tmp[(size_t)nA * 16 + sub];
                __half2 d2 = __float2half2_rn(dviA);
                a01 = __hmul2(dec2lo(sv.x), d2);
                a23 = __hmul2(dec2hi(sv.x), d2);
                a45 = __hmul2(dec2lo(sv.y), d2);
                a67 = __hmul2(dec2hi(sv.y), d2);
            }
            if (okB) {
                uint2 sv = tmp[(size_t)nB * 16 + sub];
                __half2 d2 = __float2half2_rn(dviB);
                b01 = __hmul2(dec2lo(sv.x), d2);
                b23 = __hmul2(dec2hi(sv.x), d2);
                b45 = __hmul2(dec2lo(sv.y), d2);
                b67 = __hmul2(dec2hi(sv.y), d2);
            }
        }
        int jA = okA ? row_beg[nA] : 0, endA = okA ? row_end[nA] : 0;
        int jB = okB ? row_beg[nB] : 0, endB = okB ? row_end[nB] : 0;
        while (jA < endA || jB < endB) {
            int mA = endA - jA; mA = mA < 0 ? 0 : (mA > 64 ? 64 : mA);
            int mB = endB - jB; mB = mB < 0 ? 0 : (mB > 64 ? 64 : mB);
            int sA = 0; float fA = 0.f;
            if (lane < mA) { sA = csr_src[jA + lane]; fA = dinv[sA]; }
            int sB = 0; float fB = 0.f;
            if (lane < mB) { sB = csr_src[jB + lane]; fB = dinv[sB]; }
            __half2 hA = __float2half2_rn(fA);
            __half2 hB = __float2half2_rn(fB);
            int itA = (mA + 3) >> 2, itB = (mB + 3) >> 2;
            int it = itA > itB ? itA : itB;
            int k = 0;
            for (; k + 2 <= it; k += 2) {
                int e0 = 4 * k + q, e1 = e0 + 4;
                int eA0 = (e0 < mA) ? e0 : 0, eB0 = (e0 < mB) ? e0 : 0;
                int eA1 = (e1 < mA) ? e1 : 0, eB1 = (e1 < mB) ? e1 : 0;
                int skA0 = __shfl(sA, eA0, 64), skB0 = __shfl(sB, eB0, 64);
                int skA1 = __shfl(sA, eA1, 64), skB1 = __shfl(sB, eB1, 64);
                uint2 vA0 = tmp[(size_t)skA0 * 16 + sub];
                uint2 vB0 = tmp[(size_t)skB0 * 16 + sub];
                uint2 vA1 = tmp[(size_t)skA1 * 16 + sub];
                uint2 vB1 = tmp[(size_t)skB1 * 16 + sub];
                __half2 dA0 = h2shfl(hA, eA0); if (e0 >= mA) dA0 = zero2;
                __half2 dB0 = h2shfl(hB, eB0); if (e0 >= mB) dB0 = zero2;
                __half2 dA1 = h2shfl(hA, eA1); if (e1 >= mA) dA1 = zero2;
                __half2 dB1 = h2shfl(hB, eB1); if (e1 >= mB) dB1 = zero2;
                a01 = __hfma2(dec2lo(vA0.x), dA0, a01);
                a23 = __hfma2(dec2hi(vA0.x), dA0, a23);
                a45 = __hfma2(dec2lo(vA0.y), dA0, a45);
                a67 = __hfma2(dec2hi(vA0.y), dA0, a67);
                b01 = __hfma2(dec2lo(vB0.x), dB0, b01);
                b23 = __hfma2(dec2hi(vB0.x), dB0, b23);
                b45 = __hfma2(dec2lo(vB0.y), dB0, b45);
                b67 = __hfma2(dec2hi(vB0.y), dB0, b67);
                a01 = __hfma2(dec2lo(vA1.x), dA1, a01);
                a23 = __hfma2(dec2hi(vA1.x), dA1, a23);
                a45 = __hfma2(dec2lo(vA1.y), dA1, a45);
                a67 = __hfma2(dec2hi(vA1.y), dA1, a67);
                b01 = __hfma2(dec2lo(vB1.x), dB1, b01);
                b23 = __hfma2(dec2hi(vB1.x), dB1, b23);
                b45 = __hfma2(dec2lo(vB1.y), dB1, b45);
                b67 = __hfma2(dec2hi(vB1.y), dB1, b67);
            }
            if (k < it) {
                int e = 4 * k + q;
                int eA = (e < mA) ? e : 0;
                int eB = (e < mB) ? e : 0;
                int skA = __shfl(sA, eA, 64);
                int skB = __shfl(sB, eB, 64);
                __half2 dA = h2shfl(hA, eA); if (e >= mA) dA = zero2;
                __half2 dB = h2shfl(hB, eB); if (e >= mB) dB = zero2;
                uint2 vA = tmp[(size_t)skA * 16 + sub];
                uint2 vB = tmp[(size_t)skB * 16 + sub];
                a01 = __hfma2(dec2lo(vA.x), dA, a01);
                a23 = __hfma2(dec2hi(vA.x), dA, a23);
                a45 = __hfma2(dec2lo(vA.y), dA, a45);
                a67 = __hfma2(dec2hi(vA.y), dA, a67);
                b01 = __hfma2(dec2lo(vB.x), dB, b01);
                b23 = __hfma2(dec2hi(vB.x), dB, b23);
                b45 = __hfma2(dec2lo(vB.y), dB, b45);
                b67 = __hfma2(dec2hi(vB.y), dB, b67);
            }
            jA += 64; jB += 64;
        }
#pragma unroll
        for (int off = 16; off <= 32; off <<= 1) {
            a01 = __hadd2(a01, h2shfl_xor(a01, off));
            a23 = __hadd2(a23, h2shfl_xor(a23, off));
            a45 = __hadd2(a45, h2shfl_xor(a45, off));
            a67 = __hadd2(a67, h2shfl_xor(a67, off));
            b01 = __hadd2(b01, h2shfl_xor(b01, off));
            b23 = __hadd2(b23, h2shfl_xor(b23, off));
            b45 = __hadd2(b45, h2shfl_xor(b45, off));
            b67 = __hadd2(b67, h2shfl_xor(b67, off));
        }
        if (q == 0 && okA) {
            float2 f01 = __half22float2(a01);
            float2 f23 = __half22float2(a23);
            float2 f45 = __half22float2(a45);
            float2 f67 = __half22float2(a67);
            float4 c0 = *(const float4*)&bias[sub * 8];
            float4 c1 = *(const float4*)&bias[sub * 8 + 4];
            uint4 o;
            o.x = packbf(fmaxf(dviA * f01.x + c0.x, 0.f), fmaxf(dviA * f01.y + c0.y, 0.f));
            o.y = packbf(fmaxf(dviA * f23.x + c0.z, 0.f), fmaxf(dviA * f23.y + c0.w, 0.f));
            o.z = packbf(fmaxf(dviA * f45.x + c1.x, 0.f), fmaxf(dviA * f45.y + c1.y, 0.f));
            o.w = packbf(fmaxf(dviA * f67.x + c1.z, 0.f), fmaxf(dviA * f67.y + c1.w, 0.f));
            *(uint4*)&Hs[(wave * 8 + 2 * p) * 136 + sub * 8] = o;
        }
        if (q == 0 && okB) {
            float2 f01 = __half22float2(b01);
            float2 f23 = __half22float2(b23);
            float2 f45 = __half22float2(b45);
            float2 f67 = __half22float2(b67);
            float4 c0 = *(const float4*)&bias[sub * 8];
            float4 c1 = *(const float4*)&bias[sub * 8 + 4];
            uint4 o;
            o.x = packbf(fmaxf(dviB * f01.x + c0.x, 0.f), fmaxf(dviB * f01.y + c0.y, 0.f));
            o.y = packbf(fmaxf(dviB * f23.x + c0.z, 0.f), fmaxf(dviB * f23.y + c0.w, 0.f));
            o.z = packbf(fmaxf(dviB * f45.x + c1.x, 0.f), fmaxf(dviB * f45.y + c1.y, 0.f));
            o.w = packbf(fmaxf(dviB * f67.x + c1.z, 0.f), fmaxf(dviB * f67.y + c1.w, 0.f));
            *(uint4*)&Hs[(wave * 8 + 2 * p + 1) * 136 + sub * 8] = o;
        }
    }
    __syncthreads();

    // ---- gemm2: DI=128 DO=64. wave -> row-tile w>>1, col-tiles (w&1)*2..+1
    int rt = wave >> 1, cb = (wave & 1) * 2;
    int l16 = lane & 15;
    int rbase = nbase + rt * 16;
    f32x4 acc[2];
    acc[0] = (f32x4){0.f, 0.f, 0.f, 0.f};
    acc[1] = (f32x4){0.f, 0.f, 0.f, 0.f};
#pragma unroll
    for (int kt = 0; kt < 4; ++kt) {
        short8 afrag = *(const short8*)&Hs[(rt * 16 + l16) * 136 + kt * 32 + q * 8];
        const short8* wrow = (const short8*)(Wp + (size_t)(kt * 4 + q) * 64 * 8);
#pragma unroll
        for (int c = 0; c < 2; ++c) {
            short8 bfrag = wrow[(cb + c) * 16 + l16];
            acc[c] = __builtin_amdgcn_mfma_f32_16x16x32_bf16(afrag, bfrag, acc[c], 0, 0, 0);
        }
    }
#pragma unroll
    for (int r = 0; r < 4; ++r) {
        int gr = rbase + q * 4 + r;
        float dv = dinv[gr < N ? gr : 0];
#pragma unroll
        for (int c = 0; c < 2; ++c) {
            float v = acc[c][r] * dv;
            float pp_ = __shfl_xor(v, 1, 64);
            if (((l16 & 1) == 0) && gr < N)
                *(unsigned short*)(C + (size_t)gr * 64 + (cb + c) * 16 + l16) = enc2_e5m2(v, pp_);
        }
    }
}

// --------------- K4: fused agg64 (prescaled T2) + gemm3 --------------------
// 512 threads: 8 waves x 8 nodes as 4 pairs; k-loop unrolled x2. LDS row 72.
__global__ __launch_bounds__(512) void agg64_gemm3_kernel(const uint2* __restrict__ tmp,
                                                          const float* __restrict__ bias,
                                                          const float* __restrict__ dinv,
                                                          const int* __restrict__ row_beg,
                                                          const int* __restrict__ row_end,
                                                          const int* __restrict__ csr_src,
                                                          const __hip_bfloat16* __restrict__ Wp,
                                                          unsigned char* __restrict__ C, int N) {
    __shared__ unsigned short Hs[64 * 72];
    int t = threadIdx.x;
    int wave = t >> 6, lane = t & 63;
    int o8 = lane >> 3, sub8 = lane & 7;
    int nbase = (int)blockIdx.x * 64;
    __half2 zero2 = __float2half2_rn(0.f);
    __half2 one2 = __float2half2_rn(1.f);

#pragma unroll
    for (int p = 0; p < 4; ++p) {
        int nA = nbase + wave * 8 + 2 * p;
        int nB = nA + 1;
        bool okA = nA < N, okB = nB < N;
        float dviA = dinv[okA ? nA : 0];
        float dviB = dinv[okB ? nB : 0];
        __half2 a01 = zero2, a23 = zero2, a45 = zero2, a67 = zero2;
        __half2 b01 = zero2, b23 = zero2, b45 = zero2, b67 = zero2;
        if (o8 == 0) {
            if (okA) {
                uint2 sv = tmp[(size_t)nA * 8 + sub8];
                a01 = dec2lo(sv.x); a23 = dec2hi(sv.x);
                a45 = dec2lo(sv.y); a67 = dec2hi(sv.y);
            }
            if (okB) {
                uint2 sv = tmp[(size_t)nB * 8 + sub8];
                b01 = dec2lo(sv.x); b23 = dec2hi(sv.x);
                b45 = dec2lo(sv.y); b67 = dec2hi(sv.y);
            }
        }
        int jA = okA ? row_beg[nA] : 0, endA = okA ? row_end[nA] : 0;
        int jB = okB ? row_beg[nB] : 0, endB = okB ? row_end[nB] : 0;
        while (jA < endA || jB < endB) {
            int mA = endA - jA; mA = mA < 0 ? 0 : (mA > 64 ? 64 : mA);
            int mB = endB - jB; mB = mB < 0 ? 0 : (mB > 64 ? 64 : mB);
            int sA = (lane < mA) ? csr_src[jA + lane] : 0;
            int sB = (lane < mB) ? csr_src[jB + lane] : 0;
            int itA = (mA + 7) >> 3, itB = (mB + 7) >> 3;
            int it = itA > itB ? itA : itB;
            int k = 0;
            for (; k + 2 <= it; k += 2) {
                int e0 = 8 * k + o8, e1 = e0 + 8;
                int eA0 = (e0 < mA) ? e0 : 0, eB0 = (e0 < mB) ? e0 : 0;
                int eA1 = (e1 < mA) ? e1 : 0, eB1 = (e1 < mB) ? e1 : 0;
                int skA0 = __shfl(sA, eA0, 64), skB0 = __shfl(sB, eB0, 64);
                int skA1 = __shfl(sA, eA1, 64), skB1 = __shfl(sB, eB1, 64);
                uint2 vA0 = tmp[(size_t)skA0 * 8 + sub8];
                uint2 vB0 = tmp[(size_t)skB0 * 8 + sub8];
                uint2 vA1 = tmp[(size_t)skA1 * 8 + sub8];
                uint2 vB1 = tmp[(size_t)skB1 * 8 + sub8];
                __half2 dA0 = (e0 < mA) ? one2 : zero2;
                __half2 dB0 = (e0 < mB) ? one2 : zero2;
                __half2 dA1 = (e1 < mA) ? one2 : zero2;
                __half2 dB1 = (e1 < mB) ? one2 : zero2;
                a01 = __hfma2(dec2lo(vA0.x), dA0, a01);
                a23 = __hfma2(dec2hi(vA0.x), dA0, a23);
                a45 = __hfma2(dec2lo(vA0.y), dA0, a45);
                a67 = __hfma2(dec2hi(vA0.y), dA0, a67);
                b01 = __hfma2(dec2lo(vB0.x), dB0, b01);
                b23 = __hfma2(dec2hi(vB0.x), dB0, b23);
                b45 = __hfma2(dec2lo(vB0.y), dB0, b45);
                b67 = __hfma2(dec2hi(vB0.y), dB0, b67);
                a01 = __hfma2(dec2lo(vA1.x), dA1, a01);
                a23 = __hfma2(dec2hi(vA1.x), dA1, a23);
                a45 = __hfma2(dec2lo(vA1.y), dA1, a45);
                a67 = __hfma2(dec2hi(vA1.y), dA1, a67);
                b01 = __hfma2(dec2lo(vB1.x), dB1, b01);
                b23 = __hfma2(dec2hi(vB1.x), dB1, b23);
                b45 = __hfma2(dec2lo(vB1.y), dB1, b45);
                b67 = __hfma2(dec2hi(vB1.y), dB1, b67);
            }
            if (k < it) {
                int e = 8 * k + o8;
                int eA = (e < mA) ? e : 0;
                int eB = (e < mB) ? e : 0;
                int skA = __shfl(sA, eA, 64);
                int skB = __shfl(sB, eB, 64);
                __half2 dA = (e < mA) ? one2 : zero2;
                __half2 dB = (e < mB) ? one2 : zero2;
                uint2 vA = tmp[(size_t)skA * 8 + sub8];
                uint2 vB = tmp[(size_t)skB * 8 + sub8];
                a01 = __hfma2(dec2lo(vA.x), dA, a01);
                a23 = __hfma2(dec2hi(vA.x), dA, a23);
                a45 = __hfma2(dec2lo(vA.y), dA, a45);
                a67 = __hfma2(dec2hi(vA.y), dA, a67);
                b01 = __hfma2(dec2lo(vB.x), dB, b01);
                b23 = __hfma2(dec2hi(vB.x), dB, b23);
                b45 = __hfma2(dec2lo(vB.y), dB, b45);
                b67 = __hfma2(dec2hi(vB.y), dB, b67);
            }
            jA += 64; jB += 64;
        }
#pragma unroll
        for (int off = 8; off <= 32; off <<= 1) {
            a01 = __hadd2(a01, h2shfl_xor(a01, off));
            a23 = __hadd2(a23, h2shfl_xor(a23, off));
            a45 = __hadd2(a45, h2shfl_xor(a45, off));
            a67 = __hadd2(a67, h2shfl_xor(a67, off));
            b01 = __hadd2(b01, h2shfl_xor(b01, off));
            b23 = __hadd2(b23, h2shfl_xor(b23, off));
            b45 = __hadd2(b45, h2shfl_xor(b45, off));
            b67 = __hadd2(b67, h2shfl_xor(b67, off));
        }
        if (o8 == 0 && okA) {
            float2 f01 = __half22float2(a01);
            float2 f23 = __half22float2(a23);
            float2 f45 = __half22float2(a45);
            float2 f67 = __half22float2(a67);
            float4 c0 = *(const float4*)&bias[sub8 * 8];
            float4 c1 = *(const float4*)&bias[sub8 * 8 + 4];
            uint4 o;
            o.x = packbf(fmaxf(dviA * f01.x + c0.x, 0.f), fmaxf(dviA * f01.y + c0.y, 0.f));
            o.y = packbf(fmaxf(dviA * f23.x + c0.z, 0.f), fmaxf(dviA * f23.y + c0.w, 0.f));
            o.z = packbf(fmaxf(dviA * f45.x + c1.x, 0.f), fmaxf(dviA * f45.y + c1.y, 0.f));
            o.w = packbf(fmaxf(dviA * f67.x + c1.z, 0.f), fmaxf(dviA * f67.y + c1.w, 0.f));
            *(uint4*)&Hs[(wave * 8 + 2 * p) * 72 + sub8 * 8] = o;
        }
        if (o8 == 0 && okB) {
            float2 f01 = __half22float2(b01);
            float2 f23 = __half22float2(b23);
            float2 f45 = __half22float2(b45);
            float2 f67 = __half22float2(b67);
            float4 c0 = *(const float4*)&bias[sub8 * 8];
            float4 c1 = *(const float4*)&bias[sub8 * 8 + 4];
            uint4 o;
            o.x = packbf(fmaxf(dviB * f01.x + c0.x, 0.f), fmaxf(dviB * f01.y + c0.y, 0.f));
            o.y = packbf(fmaxf(dviB * f23.x + c0.z, 0.f), fmaxf(dviB * f23.y + c0.w, 0.f));
            o.z = packbf(fmaxf(dviB * f45.x + c1.x, 0.f), fmaxf(dviB * f45.y + c1.y, 0.f));
            o.w = packbf(fmaxf(dviB * f67.x + c1.z, 0.f), fmaxf(dviB * f67.y + c1.w, 0.f));
            *(uint4*)&Hs[(wave * 8 + 2 * p + 1) * 72 + sub8 * 8] = o;
        }
    }
    __syncthreads();

    // ---- gemm3: DI=64 DO=64. wave -> row-tile w>>1, col-tiles (w&1)*2..+1
    int rt = wave >> 1, cb = (wave & 1) * 2;
    int q = lane >> 4, l16 = lane & 15;
    int rbase = nbase + rt * 16;
    f32x4 acc[2];
    acc[0] = (f32x4){0.f, 0.f, 0.f, 0.f};
    acc[1] = (f32x4){0.f, 0.f, 0.f, 0.f};
#pragma unroll
    for (int kt = 0; kt < 2; ++kt) {
        short8 afrag = *(const short8*)&Hs[(rt * 16 + l16) * 72 + kt * 32 + q * 8];
        const short8* wrow = (const short8*)(Wp + (size_t)(kt * 4 + q) * 64 * 8);
#pragma unroll
        for (int c = 0; c < 2; ++c) {
            short8 bfrag = wrow[(cb + c) * 16 + l16];
            acc[c] = __builtin_amdgcn_mfma_f32_16x16x32_bf16(afrag, bfrag, acc[c], 0, 0, 0);
        }
    }
#pragma unroll
    for (int r = 0; r < 4; ++r) {
        int gr = rbase + q * 4 + r;
        float dv = dinv[gr < N ? gr : 0];
#pragma unroll
        for (int c = 0; c < 2; ++c) {
            float v = acc[c][r] * dv;
            float pp_ = __shfl_xor(v, 1, 64);
            if (((l16 & 1) == 0) && gr < N)
                *(unsigned short*)(C + (size_t)gr * 64 + (cb + c) * 16 + l16) = enc2_e5m2(v, pp_);
        }
    }
}

// --------------- K5: fused agg64 (prescaled T3) + head ---------------------
// 512 threads: 8 waves x 8 nodes as 4 pairs; k-loop unrolled x2.
__global__ __launch_bounds__(512) void agg64_head_kernel(const uint2* __restrict__ tmp,
                                                         const float* __restrict__ bias,
                                                         const float* __restrict__ dinv,
                                                         const int* __restrict__ row_beg,
                                                         const int* __restrict__ row_end,
                                                         const int* __restrict__ csr_src,
                                                         const float* __restrict__ protos,
                                                         const float* __restrict__ Wf0,
                                                         const float* __restrict__ bf0,
                                                         const float* __restrict__ Wf1,
                                                         const float* __restrict__ bf1,
                                                         const int* __restrict__ y,
                                                         float* __restrict__ out, int N) {
    __shared__ float Hl[64 * 65];
    __shared__ float Pl[16 * 65];
    __shared__ float hh[64];
    __shared__ float pp[16];
    __shared__ float sim[64 * 17];
    __shared__ float Wf0l[128];
    __shared__ float bf0l[8];
    __shared__ float Wf1l[8];
    __shared__ float bf1l;
    int t = threadIdx.x;
    int wave = t >> 6, lane = t & 63;
    int o8 = lane >> 3, sub8 = lane & 7;
    int n0 = (int)blockIdx.x * 64;

    // prefetch head constants
    for (int idx = t; idx < 16 * 64; idx += 512) {
        int r = idx >> 6, c = idx & 63;
        Pl[r * 65 + c] = protos[idx];
    }
    if (t < 128) Wf0l[t] = Wf0[t];
    if (t < 8) { bf0l[t] = bf0[t]; Wf1l[t] = Wf1[t]; }
    if (t == 0) bf1l = bf1[0];

    __half2 zero2 = __float2half2_rn(0.f);
    __half2 one2 = __float2half2_rn(1.f);
#pragma unroll
    for (int p = 0; p < 4; ++p) {
        int nA = n0 + wave * 8 + 2 * p;
        int nB = nA + 1;
        bool okA = nA < N, okB = nB < N;
        float dviA = dinv[okA ? nA : 0];
        float dviB = dinv[okB ? nB : 0];
        __half2 a01 = zero2, a23 = zero2, a45 = zero2, a67 = zero2;
        __half2 b01 = zero2, b23 = zero2, b45 = zero2, b67 = zero2;
        if (o8 == 0) {
            if (okA) {
                uint2 sv = tmp[(size_t)nA * 8 + sub8];
                a01 = dec2lo(sv.x); a23 = dec2hi(sv.x);
                a45 = dec2lo(sv.y); a67 = dec2hi(sv.y);
            }
            if (okB) {
                uint2 sv = tmp[(size_t)nB * 8 + sub8];
                b01 = dec2lo(sv.x); b23 = dec2hi(sv.x);
                b45 = dec2lo(sv.y); b67 = dec2hi(sv.y);
            }
        }
        int jA = okA ? row_beg[nA] : 0, endA = okA ? row_end[nA] : 0;
        int jB = okB ? row_beg[nB] : 0, endB = okB ? row_end[nB] : 0;
        while (jA < endA || jB < endB) {
            int mA = endA - jA; mA = mA < 0 ? 0 : (mA > 64 ? 64 : mA);
            int mB = endB - jB; mB = mB < 0 ? 0 : (mB > 64 ? 64 : mB);
            int sA = (lane < mA) ? csr_src[jA + lane] : 0;
            int sB = (lane < mB) ? csr_src[jB + lane] : 0;
            int itA = (mA + 7) >> 3, itB = (mB + 7) >> 3;
            int it = itA > itB ? itA : itB;
            int k = 0;
            for (; k + 2 <= it; k += 2) {
                int e0 = 8 * k + o8, e1 = e0 + 8;
                int eA0 = (e0 < mA) ? e0 : 0, eB0 = (e0 < mB) ? e0 : 0;
                int eA1 = (e1 < mA) ? e1 : 0, eB1 = (e1 < mB) ? e1 : 0;
                int skA0 = __shfl(sA, eA0, 64), skB0 = __shfl(sB, eB0, 64);
                int skA1 = __shfl(sA, eA1, 64), skB1 = __shfl(sB, eB1, 64);
                uint2 vA0 = tmp[(size_t)skA0 * 8 + sub8];
                uint2 vB0 = tmp[(size_t)skB0 * 8 + sub8];
                uint2 vA1 = tmp[(size_t)skA1 * 8 + sub8];
                uint2 vB1 = tmp[(size_t)skB1 * 8 + sub8];
                __half2 dA0 = (e0 < mA) ? one2 : zero2;
                __half2 dB0 = (e0 < mB) ? one2 : zero2;
                __half2 dA1 = (e1 < mA) ? one2 : zero2;
                __half2 dB1 = (e1 < mB) ? one2 : zero2;
                a01 = __hfma2(dec2lo(vA0.x), dA0, a01);
                a23 = __hfma2(dec2hi(vA0.x), dA0, a23);
                a45 = __hfma2(dec2lo(vA0.y), dA0, a45);
                a67 = __hfma2(dec2hi(vA0.y), dA0, a67);
                b01 = __hfma2(dec2lo(vB0.x), dB0, b01);
                b23 = __hfma2(dec2hi(vB0.x), dB0, b23);
                b45 = __hfma2(dec2lo(vB0.y), dB0, b45);
                b67 = __hfma2(dec2hi(vB0.y), dB0, b67);
                a01 = __hfma2(dec2lo(vA1.x), dA1, a01);
                a23 = __hfma2(dec2hi(vA1.x), dA1, a23);
                a45 = __hfma2(dec2lo(vA1.y), dA1, a45);
                a67 = __hfma2(dec2hi(vA1.y), dA1, a67);
                b01 = __hfma2(dec2lo(vB1.x), dB1, b01);
                b23 = __hfma2(dec2hi(vB1.x), dB1, b23);
                b45 = __hfma2(dec2lo(vB1.y), dB1, b45);
                b67 = __hfma2(dec2hi(vB1.y), dB1, b67);
            }
            if (k < it) {
                int e = 8 * k + o8;
                int eA = (e < mA) ? e : 0;
                int eB = (e < mB) ? e : 0;
                int skA = __shfl(sA, eA, 64);
                int skB = __shfl(sB, eB, 64);
                __half2 dA = (e < mA) ? one2 : zero2;
                __half2 dB = (e < mB) ? one2 : zero2;
                uint2 vA = tmp[(size_t)skA * 8 + sub8];
                uint2 vB = tmp[(size_t)skB * 8 + sub8];
                a01 = __hfma2(dec2lo(vA.x), dA, a01);
                a23 = __hfma2(dec2hi(vA.x), dA, a23);
                a45 = __hfma2(dec2lo(vA.y), dA, a45);
                a67 = __hfma2(dec2hi(vA.y), dA, a67);
                b01 = __hfma2(dec2lo(vB.x), dB, b01);
                b23 = __hfma2(dec2hi(vB.x), dB, b23);
                b45 = __hfma2(dec2lo(vB.y), dB, b45);
                b67 = __hfma2(dec2hi(vB.y), dB, b67);
            }
            jA += 64; jB += 64;
        }
#pragma unroll
        for (int off = 8; off <= 32; off <<= 1) {
            a01 = __hadd2(a01, h2shfl_xor(a01, off));
            a23 = __hadd2(a23, h2shfl_xor(a23, off));
            a45 = __hadd2(a45, h2shfl_xor(a45, off));
            a67 = __hadd2(a67, h2shfl_xor(a67, off));
            b01 = __hadd2(b01, h2shfl_xor(b01, off));
            b23 = __hadd2(b23, h2shfl_xor(b23, off));
            b45 = __hadd2(b45, h2shfl_xor(b45, off));
            b67 = __hadd2(b67, h2shfl_xor(b67, off));
        }
        if (o8 == 0 && okA) {
            float2 f01 = __half22float2(a01);
            float2 f23 = __half22float2(a23);
            float2 f45 = __half22float2(a45);
            float2 f67 = __half22float2(a67);
            float4 c0 = *(const float4*)&bias[sub8 * 8];
            float4 c1 = *(const float4*)&bias[sub8 * 8 + 4];
            float* hrow = &Hl[(wave * 8 + 2 * p) * 65 + sub8 * 8];
            hrow[0] = bfround(fmaxf(dviA * f01.x + c0.x, 0.f));
            hrow[1] = bfround(fmaxf(dviA * f01.y + c0.y, 0.f));
            hrow[2] = bfround(fmaxf(dviA * f23.x + c0.z, 0.f));
            hrow[3] = bfround(fmaxf(dviA * f23.y + c0.w, 0.f));
            hrow[4] = bfround(fmaxf(dviA * f45.x + c1.x, 0.f));
            hrow[5] = bfround(fmaxf(dviA * f45.y + c1.y, 0.f));
            hrow[6] = bfround(fmaxf(dviA * f67.x + c1.z, 0.f));
            hrow[7] = bfround(fmaxf(dviA * f67.y + c1.w, 0.f));
        }
        if (o8 == 0 && okB) {
            float2 f01 = __half22float2(b01);
            float2 f23 = __half22float2(b23);
            float2 f45 = __half22float2(b45);
            float2 f67 = __half22float2(b67);
            float4 c0 = *(const float4*)&bias[sub8 * 8];
            float4 c1 = *(const float4*)&bias[sub8 * 8 + 4];
            float* hrow = &Hl[(wave * 8 + 2 * p + 1) * 65 + sub8 * 8];
            hrow[0] = bfround(fmaxf(dviB * f01.x + c0.x, 0.f));
            hrow[1] = bfround(fmaxf(dviB * f01.y + c0.y, 0.f));
            hrow[2] = bfround(fmaxf(dviB * f23.x + c0.z, 0.f));
            hrow[3] = bfround(fmaxf(dviB * f23.y + c0.w, 0.f));
            hrow[4] = bfround(fmaxf(dviB * f45.x + c1.x, 0.f));
            hrow[5] = bfround(fmaxf(dviB * f45.y + c1.y, 0.f));
            hrow[6] = bfround(fmaxf(dviB * f67.x + c1.z, 0.f));
            hrow[7] = bfround(fmaxf(dviB * f67.y + c1.w, 0.f));
        }
    }
    __syncthreads();

    if (t < 64) {
        float s = 0.0f;
        for (int k = 0; k < 64; ++k) { float v = Hl[t * 65 + k]; s += v * v; }
        hh[t] = s;
    } else if (t < 80) {
        int p = t - 64;
        float s = 0.0f;
        for (int k = 0; k < 64; ++k) { float v = Pl[p * 65 + k]; s += v * v; }
        pp[p] = s;
    }
    __syncthreads();

    if (t < 256) {
        int node = t & 63;
        int p4 = (t >> 6) * 4;
        float d0 = 0, d1 = 0, d2 = 0, d3 = 0;
        for (int k = 0; k < 64; ++k) {
            float hv = Hl[node * 65 + k];
            d0 += hv * Pl[(p4 + 0) * 65 + k];
            d1 += hv * Pl[(p4 + 1) * 65 + k];
            d2 += hv * Pl[(p4 + 2) * 65 + k];
            d3 += hv * Pl[(p4 + 3) * 65 + k];
        }
        float hhv = hh[node];
        float dd[4] = {d0, d1, d2, d3};
#pragma unroll
        for (int j = 0; j < 4; ++j) {
            float qd = hhv + pp[p4 + j] - 2.0f * dd[j];
            qd = qd > 0.0f ? qd : 0.0f;
            sim[node * 17 + p4 + j] = logf((qd + 1.0f) / (qd + 1e-4f));
        }
    }
    __syncthreads();

    if (t < 64) {
        int g = n0 + t;
        if (g < N) {
            float zacc = bf1l;
#pragma unroll
            for (int o = 0; o < 8; ++o) {
                float s = bf0l[o];
#pragma unroll
                for (int i2 = 0; i2 < 16; ++i2) s += sim[t * 17 + i2] * Wf0l[i2 * 8 + o];
                float gz = 0.5f * s * (1.0f + erff(s * 0.70710678118654752f));
                zacc += gz * Wf1l[o];
            }
            out[g] = 1.0f / (1.0f + expf(-zacc));
        }
    } else if (t < 128) {
        int g = n0 + (t - 64);
        if (g < N) out[N + g] = (float)y[g];
    }
}

// ---------------------------------------------------------------------------

extern "C" void kernel_launch(void* const* d_in, const int* in_sizes, int n_in,
                              void* d_out, int out_size, void* d_ws, size_t ws_size,
                              hipStream_t stream) {
    const float* x   = (const float*)d_in[0];
    const int*   ei  = (const int*)d_in[1];
    const int*   y   = (const int*)d_in[2];
    const float* W1  = (const float*)d_in[3];
    const float* b1  = (const float*)d_in[4];
    const float* W2  = (const float*)d_in[5];
    const float* b2  = (const float*)d_in[6];
    const float* W3  = (const float*)d_in[7];
    const float* b3  = (const float*)d_in[8];
    const float* pr  = (const float*)d_in[9];
    const float* Wf0 = (const float*)d_in[10];
    const float* bf0 = (const float*)d_in[11];
    const float* Wf1 = (const float*)d_in[12];
    const float* bf1 = (const float*)d_in[13];
    float* outp = (float*)d_out;

    const int N = in_sizes[2];       // 50000
    const int E = in_sizes[1] / 2;   // 800000
    const int NB = (N + BKT_NODES - 1) / BKT_NODES;   // 1563
    const int B = (E + EPB - 1) / EPB;                // 391 (<=512)

    char* w = (char*)d_ws;
    auto carve = [&](size_t bytes) {
        char* p = w;
        w += (bytes + 511) & ~(size_t)511;
        return p;
    };
    int*   glens   = (int*)carve((size_t)B * NB * 4);
    int*   gstart  = (int*)carve((size_t)B * NB * 4);
    int*   esort   = (int*)carve((size_t)B * EPB * 4);
    int*   row_beg = (int*)carve((size_t)N * 4);
    int*   row_end = (int*)carve((size_t)N * 4);
    float* dinv    = (float*)carve((size_t)N * 4);
    int*   csr     = (int*)carve((size_t)NB * LCAP * 4);
    __hip_bfloat16* Wp1 = (__hip_bfloat16*)carve(16384 * 2);
    __hip_bfloat16* Wp2 = (__hip_bfloat16*)carve(8192 * 2);
    __hip_bfloat16* Wp3 = (__hip_bfloat16*)carve(4096 * 2);
    unsigned char* T1b = (unsigned char*)carve((size_t)N * 128);   // e5m2
    unsigned char* T2b = (unsigned char*)carve((size_t)N * 64);    // e5m2
    unsigned char* T3b = (unsigned char*)carve((size_t)N * 64);    // e5m2

    size_t sort_lds = (size_t)(2 * NB + EPB) * 4;   // ~20.7 KB
    const int gemm1_blocks = (N + 63) / 64;          // 782
    const int node_blocks = (N + 63) / 64;           // 782

    // K1: bin+sort edges || pack weights
    sort_local_kernel<<<B + PREPB, 256, sort_lds, stream>>>(ei, E, NB, B, glens, gstart, esort,
                                                            W1, W2, W3, Wp1, Wp2, Wp3);
    // K2: CSR build || gemm1 (unscaled T1 -> fp8)
    csr_gemm1_kernel<<<NB + gemm1_blocks, 256, 0, stream>>>(esort, glens, gstart, NB, B, N,
                                                            row_beg, row_end, dinv, csr,
                                                            x, Wp1, T1b);
    // K3: agg128 (dinv gather, 2-node interleave, x2 unroll) + gemm2
    agg128_gemm2_kernel<<<node_blocks, 512, 0, stream>>>((const uint2*)T1b, b1, dinv,
                                                         row_beg, row_end, csr, Wp2, T2b, N);
    // K4: agg64 (2-node interleave, x2 unroll) + gemm3
    agg64_gemm3_kernel<<<node_blocks, 512, 0, stream>>>((const uint2*)T2b, b2, dinv,
                                                        row_beg, row_end, csr, Wp3, T3b, N);
    // K5: agg64 (2-node interleave, x2 unroll) + head
    agg64_head_kernel<<<node_blocks, 512, 0, stream>>>((const uint2*)T3b, b3, dinv,
                                                       row_beg, row_end, csr,
                                                       pr, Wf0, bf0, Wf1, bf1, y, outp, N);
}